// Round 1
// 446.145 us; speedup vs baseline: 1.0348x; 1.0348x over previous
//
#include <hip/hip_runtime.h>

#define N_NODES 100000
#define N_PAD 100352          // 392 * 256
#define NBLK 392
#define IN_FEAT 128
#define OUT_FEAT 128
#define NUM_RELS 64
#define EDGES_PER_REL 16384
#define NUM_BASES 16
#define E_TOTAL (NUM_RELS * EDGES_PER_REL)

typedef __bf16 bf16x8 __attribute__((ext_vector_type(8)));
typedef float floatx4 __attribute__((ext_vector_type(4)));

// ---------------------------------------------------------------------------
// feat (fp32) -> feat_bf16, one streaming pass. Halves the random-gather
// bytes in edge_gemm_mfma (512B/row -> 256B/row). Numerics identical to the
// previous in-kernel (__bf16) cast.
// ---------------------------------------------------------------------------
__global__ __launch_bounds__(256) void feat_to_bf16_kernel(
    const float* __restrict__ feat, __bf16* __restrict__ fb) {
  long i = ((long)blockIdx.x * 256 + threadIdx.x) * 8;   // 12.8M elements
  float4 a = *(const float4*)(feat + i);
  float4 b = *(const float4*)(feat + i + 4);
  __bf16 t8[8] = {(__bf16)a.x, (__bf16)a.y, (__bf16)a.z, (__bf16)a.w,
                  (__bf16)b.x, (__bf16)b.y, (__bf16)b.z, (__bf16)b.w};
  *(uint4*)(fb + i) = *(uint4*)t8;
}

// ---------------------------------------------------------------------------
// W composition -> bf16 k-packed layout Wp[r][kp][n][j], k = kp*8+j
// ---------------------------------------------------------------------------
__global__ __launch_bounds__(256) void compose_w_bf16_kernel(
    const float* __restrict__ weight, const float* __restrict__ w_comp,
    __bf16* __restrict__ Wp) {
  int idx = blockIdx.x * 256 + threadIdx.x;
  int r = idx >> 14;
  int off = idx & 16383;
  int j = off & 7, n = (off >> 3) & 127, kp = off >> 10;
  int k = kp * 8 + j;
  const float* wc = w_comp + r * NUM_BASES;
  float acc = 0.f;
#pragma unroll
  for (int b = 0; b < NUM_BASES; ++b)
    acc += wc[b] * weight[b * 16384 + k * 128 + n];
  Wp[idx] = (__bf16)acc;
}

// loop_weight -> bf16 k-packed layout Lp[kp][n][j]
__global__ __launch_bounds__(256) void pack_loop_w_kernel(
    const float* __restrict__ loop_w, __bf16* __restrict__ Lp) {
  int idx = blockIdx.x * 256 + threadIdx.x;    // 16384
  int j = idx & 7, n = (idx >> 3) & 127, kp = idx >> 10;
  Lp[idx] = (__bf16)loop_w[(kp * 8 + j) * 128 + n];
}

__global__ __launch_bounds__(256) void compose_w_f32_kernel(
    const float* __restrict__ weight, const float* __restrict__ w_comp,
    float* __restrict__ W) {
  int idx = blockIdx.x * 256 + threadIdx.x;
  int r = idx >> 14;
  int io = idx & 16383;
  const float* wc = w_comp + r * NUM_BASES;
  float acc = 0.f;
#pragma unroll
  for (int b = 0; b < NUM_BASES; ++b)
    acc += wc[b] * weight[b * 16384 + io];
  W[idx] = acc;
}

// ---------------------------------------------------------------------------
// out[n] = h_bias + feat[n] @ loop_weight   (MFMA bf16, 64 nodes / block)
// featb (bf16 copy) used when available: halves the feat read.
// ---------------------------------------------------------------------------
__global__ __launch_bounds__(256) void init_out_mfma(
    const float* __restrict__ feat, const __bf16* __restrict__ featb,
    const __bf16* __restrict__ Lp, const float* __restrict__ bias,
    float* __restrict__ out) {
  __shared__ __bf16 A_lds[64 * 136];
  int t = threadIdx.x;
  long base = (long)blockIdx.x * 64;
  if (featb) {
#pragma unroll
    for (int j = 0; j < 4; ++j) {
      int idx = t + j * 256;
      int e = idx >> 4, seg = idx & 15;
      long n = base + e;
      uint4 v = make_uint4(0u, 0u, 0u, 0u);
      if (n < N_NODES) v = ((const uint4*)featb)[n * 16 + seg];
      *(uint4*)&A_lds[e * 136 + seg * 8] = v;
    }
  } else {
#pragma unroll
    for (int j = 0; j < 8; ++j) {
      int idx = t + j * 256;
      int e = idx >> 5, k4 = idx & 31;
      long n = base + e;
      float4 v = make_float4(0.f, 0.f, 0.f, 0.f);
      if (n < N_NODES) v = ((const float4*)feat)[n * 32 + k4];
      __bf16 tb[4] = {(__bf16)v.x, (__bf16)v.y, (__bf16)v.z, (__bf16)v.w};
      *(ushort4*)&A_lds[e * 136 + k4 * 4] = *(ushort4*)tb;
    }
  }
  __syncthreads();

  int wave = t >> 6, lane = t & 63;
  int m16 = lane & 15, quad = lane >> 4;
  floatx4 acc[8];
#pragma unroll
  for (int nt = 0; nt < 8; ++nt) acc[nt] = (floatx4){0.f, 0.f, 0.f, 0.f};

  const __bf16* a_base = &A_lds[(wave * 16 + m16) * 136 + quad * 8];
#pragma unroll
  for (int ks = 0; ks < 4; ++ks) {
    bf16x8 a = *(const bf16x8*)(a_base + ks * 32);
    int kp = ks * 4 + quad;
#pragma unroll
    for (int nt = 0; nt < 8; ++nt) {
      bf16x8 b = *(const bf16x8*)(Lp + (kp * 128 + nt * 16 + m16) * 8);
      acc[nt] = __builtin_amdgcn_mfma_f32_16x16x32_bf16(a, b, acc[nt], 0, 0, 0);
    }
  }

  float bv[8];
#pragma unroll
  for (int nt = 0; nt < 8; ++nt) bv[nt] = bias[nt * 16 + m16];
#pragma unroll
  for (int r = 0; r < 4; ++r) {
    long n = base + wave * 16 + quad * 4 + r;
    if (n < N_NODES) {
#pragma unroll
      for (int nt = 0; nt < 8; ++nt)
        out[n * 128 + nt * 16 + m16] = acc[nt][r] + bv[nt];
    }
  }
}

// ---------------------------------------------------------------------------
// Per-chunk CSR build
// ---------------------------------------------------------------------------
__global__ __launch_bounds__(256) void zero_kernel(int* __restrict__ p) {
  p[blockIdx.x * 256 + threadIdx.x] = 0;
}

__global__ __launch_bounds__(256) void hist8_kernel(
    const int* __restrict__ dst, int* __restrict__ cnt8, int cshift) {
  int e = blockIdx.x * 256 + threadIdx.x;
  int c = e >> cshift;
  atomicAdd(&cnt8[c * N_PAD + dst[e]], 1);
}

__global__ __launch_bounds__(256) void scan1_kernel(
    const int* __restrict__ cnt, int* __restrict__ row,
    int* __restrict__ bsum) {
  __shared__ int s[256];
  int t = threadIdx.x;
  int idx = blockIdx.x * 256 + t;
  int v = cnt[idx];
  s[t] = v;
  __syncthreads();
  for (int o = 1; o < 256; o <<= 1) {
    int x = (t >= o) ? s[t - o] : 0;
    __syncthreads();
    s[t] += x;
    __syncthreads();
  }
  row[idx] = s[t] - v;
  if (t == 255) bsum[blockIdx.x] = s[t];
}

__global__ __launch_bounds__(512) void scan2_kernel(
    const int* __restrict__ bsum, int* __restrict__ boff) {
  __shared__ int s[512];
  int t = threadIdx.x;
  int v = (t < NBLK) ? bsum[blockIdx.x * NBLK + t] : 0;
  s[t] = v;
  __syncthreads();
  for (int o = 1; o < 512; o <<= 1) {
    int x = (t >= o) ? s[t - o] : 0;
    __syncthreads();
    s[t] += x;
    __syncthreads();
  }
  if (t < NBLK) boff[blockIdx.x * NBLK + t] = s[t] - v;
}

__global__ __launch_bounds__(256) void scan3_kernel(
    int* __restrict__ row, const int* __restrict__ boff,
    int* __restrict__ fill) {
  int idx = blockIdx.x * 256 + threadIdx.x;
  int v = row[idx] + boff[blockIdx.x];
  row[idx] = v;
  fill[idx] = v;
}

__global__ __launch_bounds__(256) void scatter_pos_kernel(
    const int* __restrict__ dst, int* __restrict__ fill8,
    int* __restrict__ pos, int cshift) {
  int e = blockIdx.x * 256 + threadIdx.x;
  int c = e >> cshift;
  pos[e] = atomicAdd(&fill8[c * N_PAD + dst[e]], 1);
}

// ---------------------------------------------------------------------------
// Phase A (MFMA): msg[pos[e]] = bf16((feat[src[e]] @ W[rel]) * norm[e])
// 64 edges/block, 4 waves, M=16/wave. LDS ~18KB -> 8 blocks/CU for latency
// hiding (M=32 variant measured SLOWER: 24% occupancy, 2.87 vs 3.35 TB/s).
// featb path: gathers 256B bf16 rows instead of 512B fp32 rows (halves FETCH).
// Epilogue bounces D through reused A_lds -> 256B-contiguous row stores.
// ---------------------------------------------------------------------------
__global__ __launch_bounds__(256) void edge_gemm_mfma(
    const float* __restrict__ feat, const __bf16* __restrict__ featb,
    const __bf16* __restrict__ Wp, const float* __restrict__ norm,
    const int* __restrict__ src, const int* __restrict__ pos,
    unsigned short* __restrict__ msg, int e_lo) {
  __shared__ __bf16 A_lds[64 * 136];
  __shared__ int s_src[64];
  __shared__ int s_pos[64];
  __shared__ float s_norm[64];
  int t = threadIdx.x;
  long base = (long)e_lo + (long)blockIdx.x * 64;
  int rel = (int)(base >> 14);
  const __bf16* Wr = Wp + (long)rel * (IN_FEAT * OUT_FEAT);

  if (t < 64) {
    s_src[t] = src[base + t];
    s_pos[t] = pos[base + t];
    s_norm[t] = norm[base + t];
  }
  __syncthreads();
  if (featb) {
#pragma unroll
    for (int j = 0; j < 4; ++j) {
      int idx = t + j * 256;
      int e = idx >> 4, seg = idx & 15;
      uint4 v = ((const uint4*)featb)[(long)s_src[e] * 16 + seg];
      *(uint4*)&A_lds[e * 136 + seg * 8] = v;
    }
  } else {
#pragma unroll
    for (int j = 0; j < 8; ++j) {
      int idx = t + j * 256;
      int e = idx >> 5, k4 = idx & 31;
      float4 v = ((const float4*)feat)[(long)s_src[e] * 32 + k4];
      __bf16 tb[4] = {(__bf16)v.x, (__bf16)v.y, (__bf16)v.z, (__bf16)v.w};
      *(ushort4*)&A_lds[e * 136 + k4 * 4] = *(ushort4*)tb;
    }
  }
  __syncthreads();

  int wave = t >> 6, lane = t & 63;
  int m16 = lane & 15, quad = lane >> 4;
  floatx4 acc[8];
#pragma unroll
  for (int nt = 0; nt < 8; ++nt) acc[nt] = (floatx4){0.f, 0.f, 0.f, 0.f};

  const __bf16* a_base = &A_lds[(wave * 16 + m16) * 136 + quad * 8];
#pragma unroll
  for (int ks = 0; ks < 4; ++ks) {
    bf16x8 a = *(const bf16x8*)(a_base + ks * 32);
    int kp = ks * 4 + quad;
#pragma unroll
    for (int nt = 0; nt < 8; ++nt) {
      bf16x8 b = *(const bf16x8*)(Wr + (kp * 128 + nt * 16 + m16) * 8);
      acc[nt] = __builtin_amdgcn_mfma_f32_16x16x32_bf16(a, b, acc[nt], 0, 0, 0);
    }
  }

  // D (col=lane&15, row=quad*4+r) -> norm-scaled bf16 into reused A_lds tile
  __syncthreads();
#pragma unroll
  for (int r = 0; r < 4; ++r) {
    int erow = wave * 16 + quad * 4 + r;
    float nm = s_norm[erow];
#pragma unroll
    for (int nt = 0; nt < 8; ++nt)
      A_lds[erow * 136 + nt * 16 + m16] = (__bf16)(acc[nt][r] * nm);
  }
  __syncthreads();
  // re-read 16B/lane; each msg row written as one 256B contiguous burst
#pragma unroll
  for (int it = 0; it < 4; ++it) {
    int idx = it * 256 + t;
    int row = idx >> 4, seg = idx & 15;
    uint4 v = *(const uint4*)&A_lds[row * 136 + seg * 8];
    *(uint4*)(msg + (long)s_pos[row] * 128 + seg * 8) = v;
  }
}

// ---------------------------------------------------------------------------
// Phase B: CSR gather, 2 msg rows / iter (uint2/lane = 512B per wave-iter)
// msg reads are sequential across the chunk (CSR ordered by node).
// ---------------------------------------------------------------------------
__global__ __launch_bounds__(256) void gather_csr_kernel(
    const unsigned short* __restrict__ msg, const int* __restrict__ rowc,
    float* __restrict__ out, int do_relu) {
  int wave = threadIdx.x >> 6, lane = threadIdx.x & 63;
  int n = blockIdx.x * 4 + wave;
  if (n >= N_NODES) return;
  int beg = rowc[n], end = rowc[n + 1];
  if (!do_relu && beg == end) return;
  int half = lane >> 5;
  int c4 = lane & 31;
  float s0 = 0.f, s1 = 0.f, s2 = 0.f, s3 = 0.f;
  for (int j = beg + half; j < end; j += 2) {
    uint2 m = *(const uint2*)(msg + (long)j * 128 + c4 * 4);
    s0 += __uint_as_float(m.x << 16);
    s1 += __uint_as_float(m.x & 0xFFFF0000u);
    s2 += __uint_as_float(m.y << 16);
    s3 += __uint_as_float(m.y & 0xFFFF0000u);
  }
  s0 += __shfl_down(s0, 32);
  s1 += __shfl_down(s1, 32);
  s2 += __shfl_down(s2, 32);
  s3 += __shfl_down(s3, 32);
  if (half == 0) {
    float4 o = ((float4*)out)[(long)n * 32 + c4];
    o.x += s0; o.y += s1; o.z += s2; o.w += s3;
    if (do_relu) {
      o.x = fmaxf(o.x, 0.f); o.y = fmaxf(o.y, 0.f);
      o.z = fmaxf(o.z, 0.f); o.w = fmaxf(o.w, 0.f);
    }
    ((float4*)out)[(long)n * 32 + c4] = o;
  }
}

// ---------------------------------------------------------------------------
// Fallback (tiny ws): fp32 init + GEMM + atomic scatter + relu
// ---------------------------------------------------------------------------
__global__ __launch_bounds__(256) void init_out_f32_kernel(
    const float* __restrict__ feat, const float* __restrict__ loop_w,
    const float* __restrict__ bias, float* __restrict__ out) {
  __shared__ float4 A4[64][32];
  int t = threadIdx.x;
  long base = (long)blockIdx.x * 64;
#pragma unroll
  for (int j = 0; j < 8; ++j) {
    int idx = t + j * 256;
    int e = idx >> 5, k4 = idx & 31;
    long n = base + e;
    float4 v = make_float4(0.f, 0.f, 0.f, 0.f);
    if (n < N_NODES) v = ((const float4*)feat)[n * 32 + k4];
    A4[e][k4] = v;
  }
  __syncthreads();
  int og = t & 31, eg = t >> 5;
  float acc[8][4];
#pragma unroll
  for (int j = 0; j < 8; ++j)
#pragma unroll
    for (int d = 0; d < 4; ++d) acc[j][d] = 0.f;
  const float4* W4 = (const float4*)loop_w;
  for (int k4 = 0; k4 < 32; ++k4) {
    float4 a[8];
#pragma unroll
    for (int j = 0; j < 8; ++j) a[j] = A4[eg * 8 + j][k4];
#pragma unroll
    for (int d = 0; d < 4; ++d) {
      float4 w = W4[(k4 * 4 + d) * 32 + og];
#pragma unroll
      for (int j = 0; j < 8; ++j) {
        float av = ((const float*)&a[j])[d];
        acc[j][0] += av * w.x;
        acc[j][1] += av * w.y;
        acc[j][2] += av * w.z;
        acc[j][3] += av * w.w;
      }
    }
  }
  float4 b = ((const float4*)bias)[og];
#pragma unroll
  for (int j = 0; j < 8; ++j) {
    long n = base + eg * 8 + j;
    if (n < N_NODES) {
      float4 v = make_float4(acc[j][0] + b.x, acc[j][1] + b.y,
                             acc[j][2] + b.z, acc[j][3] + b.w);
      ((float4*)out)[n * 32 + og] = v;
    }
  }
}

__global__ __launch_bounds__(256) void edge_msg_atomic_kernel(
    const float* __restrict__ feat, const float* __restrict__ W,
    const float* __restrict__ norm, const int* __restrict__ src,
    const int* __restrict__ dst, float* __restrict__ out) {
  __shared__ float4 A4[64][32];
  __shared__ int s_src[64];
  __shared__ int s_dst[64];
  __shared__ float s_norm[64];
  int t = threadIdx.x;
  long base = (long)blockIdx.x * 64;
  int rel = blockIdx.x >> 8;
  const float4* Wr4 = (const float4*)(W + (long)rel * IN_FEAT * OUT_FEAT);
  if (t < 64) {
    s_src[t] = src[base + t];
    s_dst[t] = dst[base + t];
    s_norm[t] = norm[base + t];
  }
  __syncthreads();
#pragma unroll
  for (int j = 0; j < 8; ++j) {
    int idx = t + j * 256;
    int e = idx >> 5, k4 = idx & 31;
    A4[e][k4] = ((const float4*)feat)[(long)s_src[e] * 32 + k4];
  }
  __syncthreads();
  int og = t & 31, eg = t >> 5;
  float acc[8][4];
#pragma unroll
  for (int j = 0; j < 8; ++j)
#pragma unroll
    for (int d = 0; d < 4; ++d) acc[j][d] = 0.f;
  for (int k4 = 0; k4 < 32; ++k4) {
    float4 a[8];
#pragma unroll
    for (int j = 0; j < 8; ++j) a[j] = A4[eg * 8 + j][k4];
#pragma unroll
    for (int d = 0; d < 4; ++d) {
      float4 w = Wr4[(k4 * 4 + d) * 32 + og];
#pragma unroll
      for (int j = 0; j < 8; ++j) {
        float av = ((const float*)&a[j])[d];
        acc[j][0] += av * w.x;
        acc[j][1] += av * w.y;
        acc[j][2] += av * w.z;
        acc[j][3] += av * w.w;
      }
    }
  }
#pragma unroll
  for (int j = 0; j < 8; ++j) {
    int e = eg * 8 + j;
    float nm = s_norm[e];
    float* orow = out + (long)s_dst[e] * OUT_FEAT + og * 4;
#pragma unroll
    for (int d = 0; d < 4; ++d) atomicAdd(orow + d, acc[j][d] * nm);
  }
}

__global__ __launch_bounds__(256) void relu_kernel(float* __restrict__ out) {
  int idx = blockIdx.x * 256 + threadIdx.x;
  float4 v = ((const float4*)out)[idx];
  v.x = fmaxf(v.x, 0.f);
  v.y = fmaxf(v.y, 0.f);
  v.z = fmaxf(v.z, 0.f);
  v.w = fmaxf(v.w, 0.f);
  ((float4*)out)[idx] = v;
}

extern "C" void kernel_launch(void* const* d_in, const int* in_sizes, int n_in,
                              void* d_out, int out_size, void* d_ws, size_t ws_size,
                              hipStream_t stream) {
  const float* feat   = (const float*)d_in[0];
  const float* weight = (const float*)d_in[1];
  const float* w_comp = (const float*)d_in[2];
  const float* h_bias = (const float*)d_in[3];
  const float* loop_w = (const float*)d_in[4];
  const float* norm   = (const float*)d_in[5];
  const int*   src    = (const int*)d_in[6];
  const int*   dst    = (const int*)d_in[7];
  float* out = (float*)d_out;

  const size_t SZ_WP  = (size_t)NUM_RELS * IN_FEAT * OUT_FEAT * 2;  // 2 MB
  const size_t SZ_LP  = (size_t)IN_FEAT * OUT_FEAT * 2;             // 32 KB
  const size_t SZ_FB  = (size_t)N_NODES * IN_FEAT * 2;              // 25.6 MB
  const size_t SZ_POS = (size_t)E_TOTAL * 4;                        // 4 MB

  // Config ladder: prefer fewest out-RMW passes, then the bf16-feat copy
  // (halves Phase-A gather traffic). (32,0) is the proven-fit baseline.
  int CH = 0, FB = 0;
  {
    const int chs[10] = {64, 32, 32, 16, 16, 8, 8, 4, 4, 0};
    const int fbs[10] = { 1,  1,  0,  1,  0, 1, 0, 1, 0, 0};
    for (int i = 0; i < 9 && CH == 0; ++i) {
      int ch = chs[i], fb = fbs[i], nc = NUM_RELS / ch;
      size_t need = SZ_WP + SZ_LP + (fb ? SZ_FB : 0) + SZ_POS +
                    2 * (size_t)nc * N_PAD * 4 + 2 * (size_t)nc * NBLK * 4 +
                    (size_t)ch * EDGES_PER_REL * OUT_FEAT * 2;
      if (ws_size >= need) { CH = ch; FB = fb; }
    }
  }

  if (CH > 0) {
    const int NC = NUM_RELS / CH;
    const int chunk_edges = CH * EDGES_PER_REL;
    int cshift = 14;
    for (int x = CH; x > 1; x >>= 1) ++cshift;

    char* p = (char*)d_ws;
    __bf16* Wp = (__bf16*)p;                  p += SZ_WP;
    __bf16* Lp = (__bf16*)p;                  p += SZ_LP;
    __bf16* featb = nullptr;
    if (FB) { featb = (__bf16*)p;             p += SZ_FB; }
    int* pos  = (int*)p;                      p += SZ_POS;
    int* cnt8 = (int*)p;                      p += (size_t)NC * N_PAD * 4;
    int* row8 = (int*)p;                      p += (size_t)NC * N_PAD * 4;
    int* bsum = (int*)p;                      p += (size_t)NC * NBLK * 4;
    int* boff = (int*)p;                      p += (size_t)NC * NBLK * 4;
    unsigned short* msg = (unsigned short*)p;

    if (FB)
      hipLaunchKernelGGL(feat_to_bf16_kernel,
                         dim3(N_NODES * IN_FEAT / 8 / 256), dim3(256), 0,
                         stream, feat, featb);
    hipLaunchKernelGGL(pack_loop_w_kernel, dim3(16384 / 256), dim3(256), 0,
                       stream, loop_w, Lp);
    hipLaunchKernelGGL(init_out_mfma, dim3((N_NODES + 63) / 64), dim3(256), 0,
                       stream, feat, featb, Lp, h_bias, out);
    hipLaunchKernelGGL(compose_w_bf16_kernel, dim3(NUM_RELS * 16384 / 256),
                       dim3(256), 0, stream, weight, w_comp, Wp);
    hipLaunchKernelGGL(zero_kernel, dim3(NC * NBLK), dim3(256), 0, stream, cnt8);
    hipLaunchKernelGGL(hist8_kernel, dim3(E_TOTAL / 256), dim3(256), 0, stream,
                       dst, cnt8, cshift);
    hipLaunchKernelGGL(scan1_kernel, dim3(NC * NBLK), dim3(256), 0, stream,
                       cnt8, row8, bsum);
    hipLaunchKernelGGL(scan2_kernel, dim3(NC), dim3(512), 0, stream, bsum, boff);
    hipLaunchKernelGGL(scan3_kernel, dim3(NC * NBLK), dim3(256), 0, stream,
                       row8, boff, cnt8);
    hipLaunchKernelGGL(scatter_pos_kernel, dim3(E_TOTAL / 256), dim3(256), 0,
                       stream, dst, cnt8, pos, cshift);

    for (int c = 0; c < NC; ++c) {
      hipLaunchKernelGGL(edge_gemm_mfma, dim3(chunk_edges / 64), dim3(256), 0,
                         stream, feat, featb, Wp, norm, src, pos, msg,
                         c * chunk_edges);
      hipLaunchKernelGGL(gather_csr_kernel, dim3((N_NODES + 3) / 4), dim3(256),
                         0, stream, msg, row8 + (size_t)c * N_PAD, out,
                         (c == NC - 1) ? 1 : 0);
    }
  } else {
    float* W = (float*)d_ws;
    hipLaunchKernelGGL(init_out_f32_kernel, dim3((N_NODES + 63) / 64),
                       dim3(256), 0, stream, feat, loop_w, h_bias, out);
    hipLaunchKernelGGL(compose_w_f32_kernel, dim3(NUM_RELS * 16384 / 256),
                       dim3(256), 0, stream, weight, w_comp, W);
    hipLaunchKernelGGL(edge_msg_atomic_kernel, dim3(E_TOTAL / 64), dim3(256), 0,
                       stream, feat, W, norm, src, dst, out);
    hipLaunchKernelGGL(relu_kernel, dim3((N_NODES * OUT_FEAT / 4) / 256),
                       dim3(256), 0, stream, out);
  }
}

// Round 2
// 432.138 us; speedup vs baseline: 1.0683x; 1.0324x over previous
//
#include <hip/hip_runtime.h>

#define N_NODES 100000
#define N_PAD 100352          // 392 * 256
#define NBLK 392
#define IN_FEAT 128
#define OUT_FEAT 128
#define NUM_RELS 64
#define EDGES_PER_REL 16384
#define NUM_BASES 16
#define E_TOTAL (NUM_RELS * EDGES_PER_REL)

typedef __bf16 bf16x8 __attribute__((ext_vector_type(8)));
typedef float floatx4 __attribute__((ext_vector_type(4)));

// ---------------------------------------------------------------------------
// Fused W composition (bf16 k-packed Wp[r][kp][n][j]) + loop_weight pack.
// One launch instead of two.
// ---------------------------------------------------------------------------
__global__ __launch_bounds__(256) void compose_all_bf16_kernel(
    const float* __restrict__ weight, const float* __restrict__ w_comp,
    const float* __restrict__ loop_w, __bf16* __restrict__ Wp,
    __bf16* __restrict__ Lp) {
  int gid = blockIdx.x * 256 + threadIdx.x;
  if (gid < NUM_RELS * 16384) {
    int r = gid >> 14;
    int off = gid & 16383;
    int j = off & 7, n = (off >> 3) & 127, kp = off >> 10;
    int k = kp * 8 + j;
    const float* wc = w_comp + r * NUM_BASES;
    float acc = 0.f;
#pragma unroll
    for (int b = 0; b < NUM_BASES; ++b)
      acc += wc[b] * weight[b * 16384 + k * 128 + n];
    Wp[gid] = (__bf16)acc;
  } else {
    int idx = gid - NUM_RELS * 16384;          // 16384 loop-weight elems
    int j = idx & 7, n = (idx >> 3) & 127, kp = idx >> 10;
    Lp[idx] = (__bf16)loop_w[(kp * 8 + j) * 128 + n];
  }
}

__global__ __launch_bounds__(256) void compose_w_f32_kernel(
    const float* __restrict__ weight, const float* __restrict__ w_comp,
    float* __restrict__ W) {
  int idx = blockIdx.x * 256 + threadIdx.x;
  int r = idx >> 14;
  int io = idx & 16383;
  const float* wc = w_comp + r * NUM_BASES;
  float acc = 0.f;
#pragma unroll
  for (int b = 0; b < NUM_BASES; ++b)
    acc += wc[b] * weight[b * 16384 + io];
  W[idx] = acc;
}

// ---------------------------------------------------------------------------
// out[n] = h_bias + feat[n] @ loop_weight   (MFMA bf16, 64 nodes / block)
// Also PRODUCES featb (bf16 feat copy) as a side output when non-null —
// replaces the separate feat_to_bf16 streaming pass.
// ---------------------------------------------------------------------------
__global__ __launch_bounds__(256) void init_out_mfma(
    const float* __restrict__ feat, __bf16* __restrict__ featb,
    const __bf16* __restrict__ Lp, const float* __restrict__ bias,
    float* __restrict__ out) {
  __shared__ __bf16 A_lds[64 * 136];
  int t = threadIdx.x;
  long base = (long)blockIdx.x * 64;
#pragma unroll
  for (int j = 0; j < 8; ++j) {
    int idx = t + j * 256;
    int e = idx >> 5, k4 = idx & 31;
    long n = base + e;
    float4 v = make_float4(0.f, 0.f, 0.f, 0.f);
    bool ok = (n < N_NODES);
    if (ok) v = ((const float4*)feat)[n * 32 + k4];
    __bf16 tb[4] = {(__bf16)v.x, (__bf16)v.y, (__bf16)v.z, (__bf16)v.w};
    *(ushort4*)&A_lds[e * 136 + k4 * 4] = *(ushort4*)tb;
    if (featb && ok)
      *(ushort4*)(featb + n * 128 + k4 * 4) = *(ushort4*)tb;
  }
  __syncthreads();

  int wave = t >> 6, lane = t & 63;
  int m16 = lane & 15, quad = lane >> 4;
  floatx4 acc[8];
#pragma unroll
  for (int nt = 0; nt < 8; ++nt) acc[nt] = (floatx4){0.f, 0.f, 0.f, 0.f};

  const __bf16* a_base = &A_lds[(wave * 16 + m16) * 136 + quad * 8];
#pragma unroll
  for (int ks = 0; ks < 4; ++ks) {
    bf16x8 a = *(const bf16x8*)(a_base + ks * 32);
    int kp = ks * 4 + quad;
#pragma unroll
    for (int nt = 0; nt < 8; ++nt) {
      bf16x8 b = *(const bf16x8*)(Lp + (kp * 128 + nt * 16 + m16) * 8);
      acc[nt] = __builtin_amdgcn_mfma_f32_16x16x32_bf16(a, b, acc[nt], 0, 0, 0);
    }
  }

  float bv[8];
#pragma unroll
  for (int nt = 0; nt < 8; ++nt) bv[nt] = bias[nt * 16 + m16];
#pragma unroll
  for (int r = 0; r < 4; ++r) {
    long n = base + wave * 16 + quad * 4 + r;
    if (n < N_NODES) {
#pragma unroll
      for (int nt = 0; nt < 8; ++nt)
        out[n * 128 + nt * 16 + m16] = acc[nt][r] + bv[nt];
    }
  }
}

// ---------------------------------------------------------------------------
// Per-chunk CSR build
// ---------------------------------------------------------------------------
__global__ __launch_bounds__(256) void zero_kernel(int* __restrict__ p) {
  p[blockIdx.x * 256 + threadIdx.x] = 0;
}

__global__ __launch_bounds__(256) void hist8_kernel(
    const int* __restrict__ dst, int* __restrict__ cnt8, int cshift) {
  int e = blockIdx.x * 256 + threadIdx.x;
  int c = e >> cshift;
  atomicAdd(&cnt8[c * N_PAD + dst[e]], 1);
}

__global__ __launch_bounds__(256) void scan1_kernel(
    const int* __restrict__ cnt, int* __restrict__ row,
    int* __restrict__ bsum) {
  __shared__ int s[256];
  int t = threadIdx.x;
  int idx = blockIdx.x * 256 + t;
  int v = cnt[idx];
  s[t] = v;
  __syncthreads();
  for (int o = 1; o < 256; o <<= 1) {
    int x = (t >= o) ? s[t - o] : 0;
    __syncthreads();
    s[t] += x;
    __syncthreads();
  }
  row[idx] = s[t] - v;
  if (t == 255) bsum[blockIdx.x] = s[t];
}

__global__ __launch_bounds__(512) void scan2_kernel(
    const int* __restrict__ bsum, int* __restrict__ boff) {
  __shared__ int s[512];
  int t = threadIdx.x;
  int v = (t < NBLK) ? bsum[blockIdx.x * NBLK + t] : 0;
  s[t] = v;
  __syncthreads();
  for (int o = 1; o < 512; o <<= 1) {
    int x = (t >= o) ? s[t - o] : 0;
    __syncthreads();
    s[t] += x;
    __syncthreads();
  }
  if (t < NBLK) boff[blockIdx.x * NBLK + t] = s[t] - v;
}

__global__ __launch_bounds__(256) void scan3_kernel(
    int* __restrict__ row, const int* __restrict__ boff,
    int* __restrict__ fill) {
  int idx = blockIdx.x * 256 + threadIdx.x;
  int v = row[idx] + boff[blockIdx.x];
  row[idx] = v;
  fill[idx] = v;
}

__global__ __launch_bounds__(256) void scatter_pos_kernel(
    const int* __restrict__ dst, int* __restrict__ fill8,
    int* __restrict__ pos, int cshift) {
  int e = blockIdx.x * 256 + threadIdx.x;
  int c = e >> cshift;
  pos[e] = atomicAdd(&fill8[c * N_PAD + dst[e]], 1);
}

// ---------------------------------------------------------------------------
// Phase A (MFMA): msg[pos[e]] = bf16((feat[src[e]] @ W[rel]) * norm[e])
// 64 edges/block, 4 waves. v3: Wr staged in LDS once per block (was: every
// wave re-read the full 32KB Wr from global = 1 GB L2 traffic/dispatch, the
// round-1 limiter: MfmaUtil 10%, BW 39%, nothing saturated). LDS ~51KB ->
// 3 blocks/CU = 12 waves, matching round-1 measured occupancy.
// featb path: gathers 256B bf16 rows (halves FETCH vs fp32).
// Epilogue bounces D through reused A_lds -> 256B-contiguous row stores.
// ---------------------------------------------------------------------------
__global__ __launch_bounds__(256) void edge_gemm_mfma(
    const float* __restrict__ feat, const __bf16* __restrict__ featb,
    const __bf16* __restrict__ Wp, const float* __restrict__ norm,
    const int* __restrict__ src, const int* __restrict__ pos,
    unsigned short* __restrict__ msg, int e_lo) {
  __shared__ __bf16 A_lds[64 * 136];
  __shared__ __bf16 B_lds[IN_FEAT * OUT_FEAT];   // 32 KB, k-packed like Wp
  __shared__ int s_src[64];
  __shared__ int s_pos[64];
  __shared__ float s_norm[64];
  int t = threadIdx.x;
  long base = (long)e_lo + (long)blockIdx.x * 64;
  int rel = (int)(base >> 14);
  const __bf16* Wr = Wp + (long)rel * (IN_FEAT * OUT_FEAT);

  if (t < 64) {
    s_src[t] = src[base + t];
    s_pos[t] = pos[base + t];
    s_norm[t] = norm[base + t];
  }
  // stage B (32 KB sequential, L2-hot: shared by 256 consecutive blocks)
  {
    const uint4* Wr4 = (const uint4*)Wr;
    uint4* B4 = (uint4*)B_lds;
#pragma unroll
    for (int j = 0; j < 8; ++j) B4[t + j * 256] = Wr4[t + j * 256];
  }
  __syncthreads();
  if (featb) {
#pragma unroll
    for (int j = 0; j < 4; ++j) {
      int idx = t + j * 256;
      int e = idx >> 4, seg = idx & 15;
      uint4 v = ((const uint4*)featb)[(long)s_src[e] * 16 + seg];
      *(uint4*)&A_lds[e * 136 + seg * 8] = v;
    }
  } else {
#pragma unroll
    for (int j = 0; j < 8; ++j) {
      int idx = t + j * 256;
      int e = idx >> 5, k4 = idx & 31;
      float4 v = ((const float4*)feat)[(long)s_src[e] * 32 + k4];
      __bf16 tb[4] = {(__bf16)v.x, (__bf16)v.y, (__bf16)v.z, (__bf16)v.w};
      *(ushort4*)&A_lds[e * 136 + k4 * 4] = *(ushort4*)tb;
    }
  }
  __syncthreads();

  int wave = t >> 6, lane = t & 63;
  int m16 = lane & 15, quad = lane >> 4;
  floatx4 acc[8];
#pragma unroll
  for (int nt = 0; nt < 8; ++nt) acc[nt] = (floatx4){0.f, 0.f, 0.f, 0.f};

  const __bf16* a_base = &A_lds[(wave * 16 + m16) * 136 + quad * 8];
#pragma unroll
  for (int ks = 0; ks < 4; ++ks) {
    bf16x8 a = *(const bf16x8*)(a_base + ks * 32);
    int kp = ks * 4 + quad;
#pragma unroll
    for (int nt = 0; nt < 8; ++nt) {
      bf16x8 b = *(const bf16x8*)(B_lds + (kp * 128 + nt * 16 + m16) * 8);
      acc[nt] = __builtin_amdgcn_mfma_f32_16x16x32_bf16(a, b, acc[nt], 0, 0, 0);
    }
  }

  // D (col=lane&15, row=quad*4+r) -> norm-scaled bf16 into reused A_lds tile
  __syncthreads();
#pragma unroll
  for (int r = 0; r < 4; ++r) {
    int erow = wave * 16 + quad * 4 + r;
    float nm = s_norm[erow];
#pragma unroll
    for (int nt = 0; nt < 8; ++nt)
      A_lds[erow * 136 + nt * 16 + m16] = (__bf16)(acc[nt][r] * nm);
  }
  __syncthreads();
  // re-read 16B/lane; each msg row written as one 256B contiguous burst
#pragma unroll
  for (int it = 0; it < 4; ++it) {
    int idx = it * 256 + t;
    int row = idx >> 4, seg = idx & 15;
    uint4 v = *(const uint4*)&A_lds[row * 136 + seg * 8];
    *(uint4*)(msg + (long)s_pos[row] * 128 + seg * 8) = v;
  }
}

// ---------------------------------------------------------------------------
// Phase B: CSR gather, 2 msg rows / iter (uint2/lane = 512B per wave-iter)
// msg reads are sequential across the chunk (CSR ordered by node).
// Round-1 est: ~236MB at ~5.5 TB/s -> already near BW ceiling; unchanged.
// ---------------------------------------------------------------------------
__global__ __launch_bounds__(256) void gather_csr_kernel(
    const unsigned short* __restrict__ msg, const int* __restrict__ rowc,
    float* __restrict__ out, int do_relu) {
  int wave = threadIdx.x >> 6, lane = threadIdx.x & 63;
  int n = blockIdx.x * 4 + wave;
  if (n >= N_NODES) return;
  int beg = rowc[n], end = rowc[n + 1];
  if (!do_relu && beg == end) return;
  int half = lane >> 5;
  int c4 = lane & 31;
  float s0 = 0.f, s1 = 0.f, s2 = 0.f, s3 = 0.f;
  for (int j = beg + half; j < end; j += 2) {
    uint2 m = *(const uint2*)(msg + (long)j * 128 + c4 * 4);
    s0 += __uint_as_float(m.x << 16);
    s1 += __uint_as_float(m.x & 0xFFFF0000u);
    s2 += __uint_as_float(m.y << 16);
    s3 += __uint_as_float(m.y & 0xFFFF0000u);
  }
  s0 += __shfl_down(s0, 32);
  s1 += __shfl_down(s1, 32);
  s2 += __shfl_down(s2, 32);
  s3 += __shfl_down(s3, 32);
  if (half == 0) {
    float4 o = ((float4*)out)[(long)n * 32 + c4];
    o.x += s0; o.y += s1; o.z += s2; o.w += s3;
    if (do_relu) {
      o.x = fmaxf(o.x, 0.f); o.y = fmaxf(o.y, 0.f);
      o.z = fmaxf(o.z, 0.f); o.w = fmaxf(o.w, 0.f);
    }
    ((float4*)out)[(long)n * 32 + c4] = o;
  }
}

// ---------------------------------------------------------------------------
// Fallback (tiny ws): fp32 init + GEMM + atomic scatter + relu
// ---------------------------------------------------------------------------
__global__ __launch_bounds__(256) void init_out_f32_kernel(
    const float* __restrict__ feat, const float* __restrict__ loop_w,
    const float* __restrict__ bias, float* __restrict__ out) {
  __shared__ float4 A4[64][32];
  int t = threadIdx.x;
  long base = (long)blockIdx.x * 64;
#pragma unroll
  for (int j = 0; j < 8; ++j) {
    int idx = t + j * 256;
    int e = idx >> 5, k4 = idx & 31;
    long n = base + e;
    float4 v = make_float4(0.f, 0.f, 0.f, 0.f);
    if (n < N_NODES) v = ((const float4*)feat)[n * 32 + k4];
    A4[e][k4] = v;
  }
  __syncthreads();
  int og = t & 31, eg = t >> 5;
  float acc[8][4];
#pragma unroll
  for (int j = 0; j < 8; ++j)
#pragma unroll
    for (int d = 0; d < 4; ++d) acc[j][d] = 0.f;
  const float4* W4 = (const float4*)loop_w;
  for (int k4 = 0; k4 < 32; ++k4) {
    float4 a[8];
#pragma unroll
    for (int j = 0; j < 8; ++j) a[j] = A4[eg * 8 + j][k4];
#pragma unroll
    for (int d = 0; d < 4; ++d) {
      float4 w = W4[(k4 * 4 + d) * 32 + og];
#pragma unroll
      for (int j = 0; j < 8; ++j) {
        float av = ((const float*)&a[j])[d];
        acc[j][0] += av * w.x;
        acc[j][1] += av * w.y;
        acc[j][2] += av * w.z;
        acc[j][3] += av * w.w;
      }
    }
  }
  float4 b = ((const float4*)bias)[og];
#pragma unroll
  for (int j = 0; j < 8; ++j) {
    long n = base + eg * 8 + j;
    if (n < N_NODES) {
      float4 v = make_float4(acc[j][0] + b.x, acc[j][1] + b.y,
                             acc[j][2] + b.z, acc[j][3] + b.w);
      ((float4*)out)[n * 32 + og] = v;
    }
  }
}

__global__ __launch_bounds__(256) void edge_msg_atomic_kernel(
    const float* __restrict__ feat, const float* __restrict__ W,
    const float* __restrict__ norm, const int* __restrict__ src,
    const int* __restrict__ dst, float* __restrict__ out) {
  __shared__ float4 A4[64][32];
  __shared__ int s_src[64];
  __shared__ int s_dst[64];
  __shared__ float s_norm[64];
  int t = threadIdx.x;
  long base = (long)blockIdx.x * 64;
  int rel = blockIdx.x >> 8;
  const float4* Wr4 = (const float4*)(W + (long)rel * IN_FEAT * OUT_FEAT);
  if (t < 64) {
    s_src[t] = src[base + t];
    s_dst[t] = dst[base + t];
    s_norm[t] = norm[base + t];
  }
  __syncthreads();
#pragma unroll
  for (int j = 0; j < 8; ++j) {
    int idx = t + j * 256;
    int e = idx >> 5, k4 = idx & 31;
    A4[e][k4] = ((const float4*)feat)[(long)s_src[e] * 32 + k4];
  }
  __syncthreads();
  int og = t & 31, eg = t >> 5;
  float acc[8][4];
#pragma unroll
  for (int j = 0; j < 8; ++j)
#pragma unroll
    for (int d = 0; d < 4; ++d) acc[j][d] = 0.f;
  for (int k4 = 0; k4 < 32; ++k4) {
    float4 a[8];
#pragma unroll
    for (int j = 0; j < 8; ++j) a[j] = A4[eg * 8 + j][k4];
#pragma unroll
    for (int d = 0; d < 4; ++d) {
      float4 w = Wr4[(k4 * 4 + d) * 32 + og];
#pragma unroll
      for (int j = 0; j < 8; ++j) {
        float av = ((const float*)&a[j])[d];
        acc[j][0] += av * w.x;
        acc[j][1] += av * w.y;
        acc[j][2] += av * w.z;
        acc[j][3] += av * w.w;
      }
    }
  }
#pragma unroll
  for (int j = 0; j < 8; ++j) {
    int e = eg * 8 + j;
    float nm = s_norm[e];
    float* orow = out + (long)s_dst[e] * OUT_FEAT + og * 4;
#pragma unroll
    for (int d = 0; d < 4; ++d) atomicAdd(orow + d, acc[j][d] * nm);
  }
}

__global__ __launch_bounds__(256) void relu_kernel(float* __restrict__ out) {
  int idx = blockIdx.x * 256 + threadIdx.x;
  float4 v = ((const float4*)out)[idx];
  v.x = fmaxf(v.x, 0.f);
  v.y = fmaxf(v.y, 0.f);
  v.z = fmaxf(v.z, 0.f);
  v.w = fmaxf(v.w, 0.f);
  ((float4*)out)[idx] = v;
}

extern "C" void kernel_launch(void* const* d_in, const int* in_sizes, int n_in,
                              void* d_out, int out_size, void* d_ws, size_t ws_size,
                              hipStream_t stream) {
  const float* feat   = (const float*)d_in[0];
  const float* weight = (const float*)d_in[1];
  const float* w_comp = (const float*)d_in[2];
  const float* h_bias = (const float*)d_in[3];
  const float* loop_w = (const float*)d_in[4];
  const float* norm   = (const float*)d_in[5];
  const int*   src    = (const int*)d_in[6];
  const int*   dst    = (const int*)d_in[7];
  float* out = (float*)d_out;

  const size_t SZ_WP  = (size_t)NUM_RELS * IN_FEAT * OUT_FEAT * 2;  // 2 MB
  const size_t SZ_LP  = (size_t)IN_FEAT * OUT_FEAT * 2;             // 32 KB
  const size_t SZ_FB  = (size_t)N_NODES * IN_FEAT * 2;              // 25.6 MB
  const size_t SZ_POS = (size_t)E_TOTAL * 4;                        // 4 MB

  // Config ladder: prefer fewest out-RMW passes, then the bf16-feat copy
  // (halves Phase-A gather traffic). Round 1 resolved (32,1): ws in [167,300)MB.
  int CH = 0, FB = 0;
  {
    const int chs[10] = {64, 32, 32, 16, 16, 8, 8, 4, 4, 0};
    const int fbs[10] = { 1,  1,  0,  1,  0, 1, 0, 1, 0, 0};
    for (int i = 0; i < 9 && CH == 0; ++i) {
      int ch = chs[i], fb = fbs[i], nc = NUM_RELS / ch;
      size_t need = SZ_WP + SZ_LP + (fb ? SZ_FB : 0) + SZ_POS +
                    2 * (size_t)nc * N_PAD * 4 + 2 * (size_t)nc * NBLK * 4 +
                    (size_t)ch * EDGES_PER_REL * OUT_FEAT * 2;
      if (ws_size >= need) { CH = ch; FB = fb; }
    }
  }

  if (CH > 0) {
    const int NC = NUM_RELS / CH;
    const int chunk_edges = CH * EDGES_PER_REL;
    int cshift = 14;
    for (int x = CH; x > 1; x >>= 1) ++cshift;

    char* p = (char*)d_ws;
    __bf16* Wp = (__bf16*)p;                  p += SZ_WP;
    __bf16* Lp = (__bf16*)p;                  p += SZ_LP;
    __bf16* featb = nullptr;
    if (FB) { featb = (__bf16*)p;             p += SZ_FB; }
    int* pos  = (int*)p;                      p += SZ_POS;
    int* cnt8 = (int*)p;                      p += (size_t)NC * N_PAD * 4;
    int* row8 = (int*)p;                      p += (size_t)NC * N_PAD * 4;
    int* bsum = (int*)p;                      p += (size_t)NC * NBLK * 4;
    int* boff = (int*)p;                      p += (size_t)NC * NBLK * 4;
    unsigned short* msg = (unsigned short*)p;

    hipLaunchKernelGGL(compose_all_bf16_kernel,
                       dim3((NUM_RELS * 16384 + 16384) / 256), dim3(256), 0,
                       stream, weight, w_comp, loop_w, Wp, Lp);
    hipLaunchKernelGGL(init_out_mfma, dim3((N_NODES + 63) / 64), dim3(256), 0,
                       stream, feat, featb, Lp, h_bias, out);
    hipLaunchKernelGGL(zero_kernel, dim3(NC * NBLK), dim3(256), 0, stream, cnt8);
    hipLaunchKernelGGL(hist8_kernel, dim3(E_TOTAL / 256), dim3(256), 0, stream,
                       dst, cnt8, cshift);
    hipLaunchKernelGGL(scan1_kernel, dim3(NC * NBLK), dim3(256), 0, stream,
                       cnt8, row8, bsum);
    hipLaunchKernelGGL(scan2_kernel, dim3(NC), dim3(512), 0, stream, bsum, boff);
    hipLaunchKernelGGL(scan3_kernel, dim3(NC * NBLK), dim3(256), 0, stream,
                       row8, boff, cnt8);
    hipLaunchKernelGGL(scatter_pos_kernel, dim3(E_TOTAL / 256), dim3(256), 0,
                       stream, dst, cnt8, pos, cshift);

    for (int c = 0; c < NC; ++c) {
      hipLaunchKernelGGL(edge_gemm_mfma, dim3(chunk_edges / 64), dim3(256), 0,
                         stream, feat, featb, Wp, norm, src, pos, msg,
                         c * chunk_edges);
      hipLaunchKernelGGL(gather_csr_kernel, dim3((N_NODES + 3) / 4), dim3(256),
                         0, stream, msg, row8 + (size_t)c * N_PAD, out,
                         (c == NC - 1) ? 1 : 0);
    }
  } else {
    float* W = (float*)d_ws;
    hipLaunchKernelGGL(init_out_f32_kernel, dim3((N_NODES + 63) / 64),
                       dim3(256), 0, stream, feat, loop_w, h_bias, out);
    hipLaunchKernelGGL(compose_w_f32_kernel, dim3(NUM_RELS * 16384 / 256),
                       dim3(256), 0, stream, weight, w_comp, W);
    hipLaunchKernelGGL(edge_msg_atomic_kernel, dim3(E_TOTAL / 64), dim3(256), 0,
                       stream, feat, W, norm, src, dst, out);
    hipLaunchKernelGGL(relu_kernel, dim3((N_NODES * OUT_FEAT / 4) / 256),
                       dim3(256), 0, stream, out);
  }
}

// Round 4
// 428.768 us; speedup vs baseline: 1.0767x; 1.0079x over previous
//
#include <hip/hip_runtime.h>

#define N_NODES 100000
#define N_PAD 100352          // 392 * 256
#define NBLK 392
#define IN_FEAT 128
#define OUT_FEAT 128
#define NUM_RELS 64
#define EDGES_PER_REL 16384
#define NUM_BASES 16
#define E_TOTAL (NUM_RELS * EDGES_PER_REL)

typedef __bf16 bf16x8 __attribute__((ext_vector_type(8)));
typedef float floatx4 __attribute__((ext_vector_type(4)));

// ---------------------------------------------------------------------------
// Fused W composition (bf16 k-packed Wp[r][kp][n][j]) + loop_weight pack.
// ---------------------------------------------------------------------------
__global__ __launch_bounds__(256) void compose_all_bf16_kernel(
    const float* __restrict__ weight, const float* __restrict__ w_comp,
    const float* __restrict__ loop_w, __bf16* __restrict__ Wp,
    __bf16* __restrict__ Lp) {
  int gid = blockIdx.x * 256 + threadIdx.x;
  if (gid < NUM_RELS * 16384) {
    int r = gid >> 14;
    int off = gid & 16383;
    int j = off & 7, n = (off >> 3) & 127, kp = off >> 10;
    int k = kp * 8 + j;
    const float* wc = w_comp + r * NUM_BASES;
    float acc = 0.f;
#pragma unroll
    for (int b = 0; b < NUM_BASES; ++b)
      acc += wc[b] * weight[b * 16384 + k * 128 + n];
    Wp[gid] = (__bf16)acc;
  } else {
    int idx = gid - NUM_RELS * 16384;          // 16384 loop-weight elems
    int j = idx & 7, n = (idx >> 3) & 127, kp = idx >> 10;
    Lp[idx] = (__bf16)loop_w[(kp * 8 + j) * 128 + n];
  }
}

__global__ __launch_bounds__(256) void compose_w_f32_kernel(
    const float* __restrict__ weight, const float* __restrict__ w_comp,
    float* __restrict__ W) {
  int idx = blockIdx.x * 256 + threadIdx.x;
  int r = idx >> 14;
  int io = idx & 16383;
  const float* wc = w_comp + r * NUM_BASES;
  float acc = 0.f;
#pragma unroll
  for (int b = 0; b < NUM_BASES; ++b)
    acc += wc[b] * weight[b * 16384 + io];
  W[idx] = acc;
}

// ---------------------------------------------------------------------------
// out[n] = h_bias + feat[n] @ loop_weight   (MFMA bf16, 64 nodes / block)
// Also PRODUCES featb (bf16 feat copy) as a side output when non-null.
// ---------------------------------------------------------------------------
__global__ __launch_bounds__(256) void init_out_mfma(
    const float* __restrict__ feat, __bf16* __restrict__ featb,
    const __bf16* __restrict__ Lp, const float* __restrict__ bias,
    float* __restrict__ out) {
  __shared__ __bf16 A_lds[64 * 136];
  int t = threadIdx.x;
  long base = (long)blockIdx.x * 64;
#pragma unroll
  for (int j = 0; j < 8; ++j) {
    int idx = t + j * 256;
    int e = idx >> 5, k4 = idx & 31;
    long n = base + e;
    float4 v = make_float4(0.f, 0.f, 0.f, 0.f);
    bool ok = (n < N_NODES);
    if (ok) v = ((const float4*)feat)[n * 32 + k4];
    __bf16 tb[4] = {(__bf16)v.x, (__bf16)v.y, (__bf16)v.z, (__bf16)v.w};
    *(ushort4*)&A_lds[e * 136 + k4 * 4] = *(ushort4*)tb;
    if (featb && ok)
      *(ushort4*)(featb + n * 128 + k4 * 4) = *(ushort4*)tb;
  }
  __syncthreads();

  int wave = t >> 6, lane = t & 63;
  int m16 = lane & 15, quad = lane >> 4;
  floatx4 acc[8];
#pragma unroll
  for (int nt = 0; nt < 8; ++nt) acc[nt] = (floatx4){0.f, 0.f, 0.f, 0.f};

  const __bf16* a_base = &A_lds[(wave * 16 + m16) * 136 + quad * 8];
#pragma unroll
  for (int ks = 0; ks < 4; ++ks) {
    bf16x8 a = *(const bf16x8*)(a_base + ks * 32);
    int kp = ks * 4 + quad;
#pragma unroll
    for (int nt = 0; nt < 8; ++nt) {
      bf16x8 b = *(const bf16x8*)(Lp + (kp * 128 + nt * 16 + m16) * 8);
      acc[nt] = __builtin_amdgcn_mfma_f32_16x16x32_bf16(a, b, acc[nt], 0, 0, 0);
    }
  }

  float bv[8];
#pragma unroll
  for (int nt = 0; nt < 8; ++nt) bv[nt] = bias[nt * 16 + m16];
#pragma unroll
  for (int r = 0; r < 4; ++r) {
    long n = base + wave * 16 + quad * 4 + r;
    if (n < N_NODES) {
#pragma unroll
      for (int nt = 0; nt < 8; ++nt)
        out[n * 128 + nt * 16 + m16] = acc[nt][r] + bv[nt];
    }
  }
}

// ---------------------------------------------------------------------------
// Per-chunk CSR build
// ---------------------------------------------------------------------------
__global__ __launch_bounds__(256) void zero_kernel(int* __restrict__ p) {
  p[blockIdx.x * 256 + threadIdx.x] = 0;
}

__global__ __launch_bounds__(256) void hist8_kernel(
    const int* __restrict__ dst, int* __restrict__ cnt8, int cshift) {
  int e = blockIdx.x * 256 + threadIdx.x;
  int c = e >> cshift;
  atomicAdd(&cnt8[c * N_PAD + dst[e]], 1);
}

__global__ __launch_bounds__(256) void scan1_kernel(
    const int* __restrict__ cnt, int* __restrict__ row,
    int* __restrict__ bsum) {
  __shared__ int s[256];
  int t = threadIdx.x;
  int idx = blockIdx.x * 256 + t;
  int v = cnt[idx];
  s[t] = v;
  __syncthreads();
  for (int o = 1; o < 256; o <<= 1) {
    int x = (t >= o) ? s[t - o] : 0;
    __syncthreads();
    s[t] += x;
    __syncthreads();
  }
  row[idx] = s[t] - v;
  if (t == 255) bsum[blockIdx.x] = s[t];
}

__global__ __launch_bounds__(512) void scan2_kernel(
    const int* __restrict__ bsum, int* __restrict__ boff) {
  __shared__ int s[512];
  int t = threadIdx.x;
  int v = (t < NBLK) ? bsum[blockIdx.x * NBLK + t] : 0;
  s[t] = v;
  __syncthreads();
  for (int o = 1; o < 512; o <<= 1) {
    int x = (t >= o) ? s[t - o] : 0;
    __syncthreads();
    s[t] += x;
    __syncthreads();
  }
  if (t < NBLK) boff[blockIdx.x * NBLK + t] = s[t] - v;
}

__global__ __launch_bounds__(256) void scan3_kernel(
    int* __restrict__ row, const int* __restrict__ boff,
    int* __restrict__ fill) {
  int idx = blockIdx.x * 256 + threadIdx.x;
  int v = row[idx] + boff[blockIdx.x];
  row[idx] = v;
  fill[idx] = v;
}

__global__ __launch_bounds__(256) void scatter_pos_kernel(
    const int* __restrict__ dst, int* __restrict__ fill8,
    int* __restrict__ pos, int cshift) {
  int e = blockIdx.x * 256 + threadIdx.x;
  int c = e >> cshift;
  pos[e] = atomicAdd(&fill8[c * N_PAD + dst[e]], 1);
}

// ---------------------------------------------------------------------------
// Phase A (MFMA): msg[pos[e]] = bf16((feat[src[e]] @ W[rel]) * norm[e])
// 64 edges/block, 4 waves. v4: A gathered DIRECTLY into MFMA fragment regs
// (lane (m16,quad) reads 4x16B slices of featb row src[base+wave*16+m16]) —
// removes the A LDS round-trip and 1 barrier that serialized the ~700cy
// random-gather latency (round-2 limiter: occupancy 27%, nothing saturated).
// LDS = B only (32KB, reused post-barrier as the D-bounce tile) -> 4 blk/CU.
// Epilogue bounces D through LDS -> 256B-contiguous row stores.
// ---------------------------------------------------------------------------
__global__ __launch_bounds__(256) void edge_gemm_mfma(
    const float* __restrict__ feat, const __bf16* __restrict__ featb,
    const __bf16* __restrict__ Wp, const float* __restrict__ norm,
    const int* __restrict__ src, const int* __restrict__ pos,
    unsigned short* __restrict__ msg, int e_lo) {
  __shared__ __bf16 B_lds[IN_FEAT * OUT_FEAT];   // 32 KB; D-bounce reuse
  __shared__ int s_pos[64];
  int t = threadIdx.x;
  long base = (long)e_lo + (long)blockIdx.x * 64;
  int rel = (int)(base >> 14);
  const __bf16* Wr = Wp + (long)rel * (IN_FEAT * OUT_FEAT);

  if (t < 64) s_pos[t] = pos[base + t];

  // stage B (32 KB sequential, L2-hot: shared by 256 consecutive blocks)
  {
    const uint4* Wr4 = (const uint4*)Wr;
    uint4* B4 = (uint4*)B_lds;
#pragma unroll
    for (int j = 0; j < 8; ++j) B4[t + j * 256] = Wr4[t + j * 256];
  }

  int wave = t >> 6, lane = t & 63;
  int m16 = lane & 15, quad = lane >> 4;

  // A fragments straight from global: lane reads 4x16B of one featb row
  int srow = src[base + wave * 16 + m16];
  bf16x8 a[4];
  if (featb) {
    const __bf16* ap = featb + (long)srow * 128 + quad * 8;
#pragma unroll
    for (int ks = 0; ks < 4; ++ks) a[ks] = *(const bf16x8*)(ap + ks * 32);
  } else {
    const float* fp = feat + (long)srow * 128 + quad * 8;
#pragma unroll
    for (int ks = 0; ks < 4; ++ks) {
      float4 lo = *(const float4*)(fp + ks * 32);
      float4 hi = *(const float4*)(fp + ks * 32 + 4);
      __bf16 tb[8] = {(__bf16)lo.x, (__bf16)lo.y, (__bf16)lo.z, (__bf16)lo.w,
                      (__bf16)hi.x, (__bf16)hi.y, (__bf16)hi.z, (__bf16)hi.w};
      a[ks] = *(bf16x8*)tb;
    }
  }
  // norm for this lane's 4 output rows (quad*4+r of the wave's 16-edge tile)
  float nm[4];
#pragma unroll
  for (int r = 0; r < 4; ++r)
    nm[r] = norm[base + wave * 16 + quad * 4 + r];

  __syncthreads();   // B_lds ready (a[] guarded by compiler vmcnt)

  floatx4 acc[8];
#pragma unroll
  for (int nt = 0; nt < 8; ++nt) acc[nt] = (floatx4){0.f, 0.f, 0.f, 0.f};
#pragma unroll
  for (int ks = 0; ks < 4; ++ks) {
    int kp = ks * 4 + quad;
#pragma unroll
    for (int nt = 0; nt < 8; ++nt) {
      bf16x8 b = *(const bf16x8*)(B_lds + (kp * 128 + nt * 16 + m16) * 8);
      acc[nt] = __builtin_amdgcn_mfma_f32_16x16x32_bf16(a[ks], b, acc[nt], 0, 0, 0);
    }
  }

  __syncthreads();   // all waves done reading B -> reuse B_lds as D tile
  // D (col=lane&15, row=quad*4+r) -> norm-scaled bf16, pad-136 layout
#pragma unroll
  for (int r = 0; r < 4; ++r) {
    int erow = wave * 16 + quad * 4 + r;
#pragma unroll
    for (int nt = 0; nt < 8; ++nt)
      B_lds[erow * 136 + nt * 16 + m16] = (__bf16)(acc[nt][r] * nm[r]);
  }
  __syncthreads();
  // re-read 16B/lane; each msg row written as one 256B contiguous burst
#pragma unroll
  for (int it = 0; it < 4; ++it) {
    int idx = it * 256 + t;
    int row = idx >> 4, seg = idx & 15;
    uint4 v = *(const uint4*)&B_lds[row * 136 + seg * 8];
    *(uint4*)(msg + (long)s_pos[row] * 128 + seg * 8) = v;
  }
}

// ---------------------------------------------------------------------------
// Phase B: CSR gather, 2 msg rows / iter (uint2/lane = 512B per wave-iter)
// ---------------------------------------------------------------------------
__global__ __launch_bounds__(256) void gather_csr_kernel(
    const unsigned short* __restrict__ msg, const int* __restrict__ rowc,
    float* __restrict__ out, int do_relu) {
  int wave = threadIdx.x >> 6, lane = threadIdx.x & 63;
  int n = blockIdx.x * 4 + wave;
  if (n >= N_NODES) return;
  int beg = rowc[n], end = rowc[n + 1];
  if (!do_relu && beg == end) return;
  int half = lane >> 5;
  int c4 = lane & 31;
  float s0 = 0.f, s1 = 0.f, s2 = 0.f, s3 = 0.f;
  for (int j = beg + half; j < end; j += 2) {
    uint2 m = *(const uint2*)(msg + (long)j * 128 + c4 * 4);
    s0 += __uint_as_float(m.x << 16);
    s1 += __uint_as_float(m.x & 0xFFFF0000u);
    s2 += __uint_as_float(m.y << 16);
    s3 += __uint_as_float(m.y & 0xFFFF0000u);
  }
  s0 += __shfl_down(s0, 32);
  s1 += __shfl_down(s1, 32);
  s2 += __shfl_down(s2, 32);
  s3 += __shfl_down(s3, 32);
  if (half == 0) {
    float4 o = ((float4*)out)[(long)n * 32 + c4];
    o.x += s0; o.y += s1; o.z += s2; o.w += s3;
    if (do_relu) {
      o.x = fmaxf(o.x, 0.f); o.y = fmaxf(o.y, 0.f);
      o.z = fmaxf(o.z, 0.f); o.w = fmaxf(o.w, 0.f);
    }
    ((float4*)out)[(long)n * 32 + c4] = o;
  }
}

// ---------------------------------------------------------------------------
// Fallback (tiny ws): fp32 init + GEMM + atomic scatter + relu
// ---------------------------------------------------------------------------
__global__ __launch_bounds__(256) void init_out_f32_kernel(
    const float* __restrict__ feat, const float* __restrict__ loop_w,
    const float* __restrict__ bias, float* __restrict__ out) {
  __shared__ float4 A4[64][32];
  int t = threadIdx.x;
  long base = (long)blockIdx.x * 64;
#pragma unroll
  for (int j = 0; j < 8; ++j) {
    int idx = t + j * 256;
    int e = idx >> 5, k4 = idx & 31;
    long n = base + e;
    float4 v = make_float4(0.f, 0.f, 0.f, 0.f);
    if (n < N_NODES) v = ((const float4*)feat)[n * 32 + k4];
    A4[e][k4] = v;
  }
  __syncthreads();
  int og = t & 31, eg = t >> 5;
  float acc[8][4];
#pragma unroll
  for (int j = 0; j < 8; ++j)
#pragma unroll
    for (int d = 0; d < 4; ++d) acc[j][d] = 0.f;
  const float4* W4 = (const float4*)loop_w;
  for (int k4 = 0; k4 < 32; ++k4) {
    float4 a[8];
#pragma unroll
    for (int j = 0; j < 8; ++j) a[j] = A4[eg * 8 + j][k4];
#pragma unroll
    for (int d = 0; d < 4; ++d) {
      float4 w = W4[(k4 * 4 + d) * 32 + og];
#pragma unroll
      for (int j = 0; j < 8; ++j) {
        float av = ((const float*)&a[j])[d];
        acc[j][0] += av * w.x;
        acc[j][1] += av * w.y;
        acc[j][2] += av * w.z;
        acc[j][3] += av * w.w;
      }
    }
  }
  float4 b = ((const float4*)bias)[og];
#pragma unroll
  for (int j = 0; j < 8; ++j) {
    long n = base + eg * 8 + j;
    if (n < N_NODES) {
      float4 v = make_float4(acc[j][0] + b.x, acc[j][1] + b.y,
                             acc[j][2] + b.z, acc[j][3] + b.w);
      ((float4*)out)[n * 32 + og] = v;
    }
  }
}

__global__ __launch_bounds__(256) void edge_msg_atomic_kernel(
    const float* __restrict__ feat, const float* __restrict__ W,
    const float* __restrict__ norm, const int* __restrict__ src,
    const int* __restrict__ dst, float* __restrict__ out) {
  __shared__ float4 A4[64][32];
  __shared__ int s_src[64];
  __shared__ int s_dst[64];
  __shared__ float s_norm[64];
  int t = threadIdx.x;
  long base = (long)blockIdx.x * 64;
  int rel = blockIdx.x >> 8;
  const float4* Wr4 = (const float4*)(W + (long)rel * IN_FEAT * OUT_FEAT);
  if (t < 64) {
    s_src[t] = src[base + t];
    s_dst[t] = dst[base + t];
    s_norm[t] = norm[base + t];
  }
  __syncthreads();
#pragma unroll
  for (int j = 0; j < 8; ++j) {
    int idx = t + j * 256;
    int e = idx >> 5, k4 = idx & 31;
    A4[e][k4] = ((const float4*)feat)[(long)s_src[e] * 32 + k4];
  }
  __syncthreads();
  int og = t & 31, eg = t >> 5;
  float acc[8][4];
#pragma unroll
  for (int j = 0; j < 8; ++j)
#pragma unroll
    for (int d = 0; d < 4; ++d) acc[j][d] = 0.f;
  for (int k4 = 0; k4 < 32; ++k4) {
    float4 a[8];
#pragma unroll
    for (int j = 0; j < 8; ++j) a[j] = A4[eg * 8 + j][k4];
#pragma unroll
    for (int d = 0; d < 4; ++d) {
      float4 w = Wr4[(k4 * 4 + d) * 32 + og];
#pragma unroll
      for (int j = 0; j < 8; ++j) {
        float av = ((const float*)&a[j])[d];
        acc[j][0] += av * w.x;
        acc[j][1] += av * w.y;
        acc[j][2] += av * w.z;
        acc[j][3] += av * w.w;
      }
    }
  }
#pragma unroll
  for (int j = 0; j < 8; ++j) {
    int e = eg * 8 + j;
    float nm = s_norm[e];
    float* orow = out + (long)s_dst[e] * OUT_FEAT + og * 4;
#pragma unroll
    for (int d = 0; d < 4; ++d) atomicAdd(orow + d, acc[j][d] * nm);
  }
}

__global__ __launch_bounds__(256) void relu_kernel(float* __restrict__ out) {
  int idx = blockIdx.x * 256 + threadIdx.x;
  float4 v = ((const float4*)out)[idx];
  v.x = fmaxf(v.x, 0.f);
  v.y = fmaxf(v.y, 0.f);
  v.z = fmaxf(v.z, 0.f);
  v.w = fmaxf(v.w, 0.f);
  ((float4*)out)[idx] = v;
}

extern "C" void kernel_launch(void* const* d_in, const int* in_sizes, int n_in,
                              void* d_out, int out_size, void* d_ws, size_t ws_size,
                              hipStream_t stream) {
  const float* feat   = (const float*)d_in[0];
  const float* weight = (const float*)d_in[1];
  const float* w_comp = (const float*)d_in[2];
  const float* h_bias = (const float*)d_in[3];
  const float* loop_w = (const float*)d_in[4];
  const float* norm   = (const float*)d_in[5];
  const int*   src    = (const int*)d_in[6];
  const int*   dst    = (const int*)d_in[7];
  float* out = (float*)d_out;

  const size_t SZ_WP  = (size_t)NUM_RELS * IN_FEAT * OUT_FEAT * 2;  // 2 MB
  const size_t SZ_LP  = (size_t)IN_FEAT * OUT_FEAT * 2;             // 32 KB
  const size_t SZ_FB  = (size_t)N_NODES * IN_FEAT * 2;              // 25.6 MB
  const size_t SZ_POS = (size_t)E_TOTAL * 4;                        // 4 MB

  // Config ladder: prefer fewest out-RMW passes, then the bf16-feat copy
  // (halves Phase-A gather traffic). Rounds 1-2 resolved (32,1).
  int CH = 0, FB = 0;
  {
    const int chs[10] = {64, 32, 32, 16, 16, 8, 8, 4, 4, 0};
    const int fbs[10] = { 1,  1,  0,  1,  0, 1, 0, 1, 0, 0};
    for (int i = 0; i < 9 && CH == 0; ++i) {
      int ch = chs[i], fb = fbs[i], nc = NUM_RELS / ch;
      size_t need = SZ_WP + SZ_LP + (fb ? SZ_FB : 0) + SZ_POS +
                    2 * (size_t)nc * N_PAD * 4 + 2 * (size_t)nc * NBLK * 4 +
                    (size_t)ch * EDGES_PER_REL * OUT_FEAT * 2;
      if (ws_size >= need) { CH = ch; FB = fb; }
    }
  }

  if (CH > 0) {
    const int NC = NUM_RELS / CH;
    const int chunk_edges = CH * EDGES_PER_REL;
    int cshift = 14;
    for (int x = CH; x > 1; x >>= 1) ++cshift;

    char* p = (char*)d_ws;
    __bf16* Wp = (__bf16*)p;                  p += SZ_WP;
    __bf16* Lp = (__bf16*)p;                  p += SZ_LP;
    __bf16* featb = nullptr;
    if (FB) { featb = (__bf16*)p;             p += SZ_FB; }
    int* pos  = (int*)p;                      p += SZ_POS;
    int* cnt8 = (int*)p;                      p += (size_t)NC * N_PAD * 4;
    int* row8 = (int*)p;                      p += (size_t)NC * N_PAD * 4;
    int* bsum = (int*)p;                      p += (size_t)NC * NBLK * 4;
    int* boff = (int*)p;                      p += (size_t)NC * NBLK * 4;
    unsigned short* msg = (unsigned short*)p;

    hipLaunchKernelGGL(compose_all_bf16_kernel,
                       dim3((NUM_RELS * 16384 + 16384) / 256), dim3(256), 0,
                       stream, weight, w_comp, loop_w, Wp, Lp);
    hipLaunchKernelGGL(init_out_mfma, dim3((N_NODES + 63) / 64), dim3(256), 0,
                       stream, feat, featb, Lp, h_bias, out);
    hipLaunchKernelGGL(zero_kernel, dim3(NC * NBLK), dim3(256), 0, stream, cnt8);
    hipLaunchKernelGGL(hist8_kernel, dim3(E_TOTAL / 256), dim3(256), 0, stream,
                       dst, cnt8, cshift);
    hipLaunchKernelGGL(scan1_kernel, dim3(NC * NBLK), dim3(256), 0, stream,
                       cnt8, row8, bsum);
    hipLaunchKernelGGL(scan2_kernel, dim3(NC), dim3(512), 0, stream, bsum, boff);
    hipLaunchKernelGGL(scan3_kernel, dim3(NC * NBLK), dim3(256), 0, stream,
                       row8, boff, cnt8);
    hipLaunchKernelGGL(scatter_pos_kernel, dim3(E_TOTAL / 256), dim3(256), 0,
                       stream, dst, cnt8, pos, cshift);

    for (int c = 0; c < NC; ++c) {
      hipLaunchKernelGGL(edge_gemm_mfma, dim3(chunk_edges / 64), dim3(256), 0,
                         stream, feat, featb, Wp, norm, src, pos, msg,
                         c * chunk_edges);
      hipLaunchKernelGGL(gather_csr_kernel, dim3((N_NODES + 3) / 4), dim3(256),
                         0, stream, msg, row8 + (size_t)c * N_PAD, out,
                         (c == NC - 1) ? 1 : 0);
    }
  } else {
    float* W = (float*)d_ws;
    hipLaunchKernelGGL(init_out_f32_kernel, dim3((N_NODES + 63) / 64),
                       dim3(256), 0, stream, feat, loop_w, h_bias, out);
    hipLaunchKernelGGL(compose_w_f32_kernel, dim3(NUM_RELS * 16384 / 256),
                       dim3(256), 0, stream, weight, w_comp, W);
    hipLaunchKernelGGL(edge_msg_atomic_kernel, dim3(E_TOTAL / 64), dim3(256), 0,
                       stream, feat, W, norm, src, dst, out);
    hipLaunchKernelGGL(relu_kernel, dim3((N_NODES * OUT_FEAT / 4) / 256),
                       dim3(256), 0, stream, out);
  }
}

// Round 5
// 421.816 us; speedup vs baseline: 1.0945x; 1.0165x over previous
//
#include <hip/hip_runtime.h>

#define N_NODES 100000
#define N_PAD 100352          // 392 * 256
#define NBLK 392
#define IN_FEAT 128
#define OUT_FEAT 128
#define NUM_RELS 64
#define EDGES_PER_REL 16384
#define NUM_BASES 16
#define E_TOTAL (NUM_RELS * EDGES_PER_REL)
#define TPB 4                 // 64-edge tiles per block in edge_gemm (256 edges)

typedef __bf16 bf16x8 __attribute__((ext_vector_type(8)));
typedef float floatx4 __attribute__((ext_vector_type(4)));

// ---------------------------------------------------------------------------
// Fused W composition (bf16 k-packed Wp[r][kp][n][j]) + loop_weight pack.
// ---------------------------------------------------------------------------
__global__ __launch_bounds__(256) void compose_all_bf16_kernel(
    const float* __restrict__ weight, const float* __restrict__ w_comp,
    const float* __restrict__ loop_w, __bf16* __restrict__ Wp,
    __bf16* __restrict__ Lp) {
  int gid = blockIdx.x * 256 + threadIdx.x;
  if (gid < NUM_RELS * 16384) {
    int r = gid >> 14;
    int off = gid & 16383;
    int j = off & 7, n = (off >> 3) & 127, kp = off >> 10;
    int k = kp * 8 + j;
    const float* wc = w_comp + r * NUM_BASES;
    float acc = 0.f;
#pragma unroll
    for (int b = 0; b < NUM_BASES; ++b)
      acc += wc[b] * weight[b * 16384 + k * 128 + n];
    Wp[gid] = (__bf16)acc;
  } else {
    int idx = gid - NUM_RELS * 16384;          // 16384 loop-weight elems
    int j = idx & 7, n = (idx >> 3) & 127, kp = idx >> 10;
    Lp[idx] = (__bf16)loop_w[(kp * 8 + j) * 128 + n];
  }
}

__global__ __launch_bounds__(256) void compose_w_f32_kernel(
    const float* __restrict__ weight, const float* __restrict__ w_comp,
    float* __restrict__ W) {
  int idx = blockIdx.x * 256 + threadIdx.x;
  int r = idx >> 14;
  int io = idx & 16383;
  const float* wc = w_comp + r * NUM_BASES;
  float acc = 0.f;
#pragma unroll
  for (int b = 0; b < NUM_BASES; ++b)
    acc += wc[b] * weight[b * 16384 + io];
  W[idx] = acc;
}

// ---------------------------------------------------------------------------
// out[n] = h_bias + feat[n] @ loop_weight   (MFMA bf16, 64 nodes / block)
// Also PRODUCES featb (bf16 feat copy) as a side output when non-null.
// ---------------------------------------------------------------------------
__global__ __launch_bounds__(256) void init_out_mfma(
    const float* __restrict__ feat, __bf16* __restrict__ featb,
    const __bf16* __restrict__ Lp, const float* __restrict__ bias,
    float* __restrict__ out) {
  __shared__ __bf16 A_lds[64 * 136];
  int t = threadIdx.x;
  long base = (long)blockIdx.x * 64;
#pragma unroll
  for (int j = 0; j < 8; ++j) {
    int idx = t + j * 256;
    int e = idx >> 5, k4 = idx & 31;
    long n = base + e;
    float4 v = make_float4(0.f, 0.f, 0.f, 0.f);
    bool ok = (n < N_NODES);
    if (ok) v = ((const float4*)feat)[n * 32 + k4];
    __bf16 tb[4] = {(__bf16)v.x, (__bf16)v.y, (__bf16)v.z, (__bf16)v.w};
    *(ushort4*)&A_lds[e * 136 + k4 * 4] = *(ushort4*)tb;
    if (featb && ok)
      *(ushort4*)(featb + n * 128 + k4 * 4) = *(ushort4*)tb;
  }
  __syncthreads();

  int wave = t >> 6, lane = t & 63;
  int m16 = lane & 15, quad = lane >> 4;
  floatx4 acc[8];
#pragma unroll
  for (int nt = 0; nt < 8; ++nt) acc[nt] = (floatx4){0.f, 0.f, 0.f, 0.f};

  const __bf16* a_base = &A_lds[(wave * 16 + m16) * 136 + quad * 8];
#pragma unroll
  for (int ks = 0; ks < 4; ++ks) {
    bf16x8 a = *(const bf16x8*)(a_base + ks * 32);
    int kp = ks * 4 + quad;
#pragma unroll
    for (int nt = 0; nt < 8; ++nt) {
      bf16x8 b = *(const bf16x8*)(Lp + (kp * 128 + nt * 16 + m16) * 8);
      acc[nt] = __builtin_amdgcn_mfma_f32_16x16x32_bf16(a, b, acc[nt], 0, 0, 0);
    }
  }

  float bv[8];
#pragma unroll
  for (int nt = 0; nt < 8; ++nt) bv[nt] = bias[nt * 16 + m16];
#pragma unroll
  for (int r = 0; r < 4; ++r) {
    long n = base + wave * 16 + quad * 4 + r;
    if (n < N_NODES) {
#pragma unroll
      for (int nt = 0; nt < 8; ++nt)
        out[n * 128 + nt * 16 + m16] = acc[nt][r] + bv[nt];
    }
  }
}

// ---------------------------------------------------------------------------
// Per-chunk CSR build
// ---------------------------------------------------------------------------
__global__ __launch_bounds__(256) void zero_kernel(int* __restrict__ p) {
  p[blockIdx.x * 256 + threadIdx.x] = 0;
}

__global__ __launch_bounds__(256) void hist8_kernel(
    const int* __restrict__ dst, int* __restrict__ cnt8, int cshift) {
  int e = blockIdx.x * 256 + threadIdx.x;
  int c = e >> cshift;
  atomicAdd(&cnt8[c * N_PAD + dst[e]], 1);
}

__global__ __launch_bounds__(256) void scan1_kernel(
    const int* __restrict__ cnt, int* __restrict__ row,
    int* __restrict__ bsum) {
  __shared__ int s[256];
  int t = threadIdx.x;
  int idx = blockIdx.x * 256 + t;
  int v = cnt[idx];
  s[t] = v;
  __syncthreads();
  for (int o = 1; o < 256; o <<= 1) {
    int x = (t >= o) ? s[t - o] : 0;
    __syncthreads();
    s[t] += x;
    __syncthreads();
  }
  row[idx] = s[t] - v;
  if (t == 255) bsum[blockIdx.x] = s[t];
}

__global__ __launch_bounds__(512) void scan2_kernel(
    const int* __restrict__ bsum, int* __restrict__ boff) {
  __shared__ int s[512];
  int t = threadIdx.x;
  int v = (t < NBLK) ? bsum[blockIdx.x * NBLK + t] : 0;
  s[t] = v;
  __syncthreads();
  for (int o = 1; o < 512; o <<= 1) {
    int x = (t >= o) ? s[t - o] : 0;
    __syncthreads();
    s[t] += x;
    __syncthreads();
  }
  if (t < NBLK) boff[blockIdx.x * NBLK + t] = s[t] - v;
}

__global__ __launch_bounds__(256) void scan3_kernel(
    int* __restrict__ row, const int* __restrict__ boff,
    int* __restrict__ fill) {
  int idx = blockIdx.x * 256 + threadIdx.x;
  int v = row[idx] + boff[blockIdx.x];
  row[idx] = v;
  fill[idx] = v;
}

__global__ __launch_bounds__(256) void scatter_pos_kernel(
    const int* __restrict__ dst, int* __restrict__ fill8,
    int* __restrict__ pos, int cshift) {
  int e = blockIdx.x * 256 + threadIdx.x;
  int c = e >> cshift;
  pos[e] = atomicAdd(&fill8[c * N_PAD + dst[e]], 1);
}

// ---------------------------------------------------------------------------
// Phase A (MFMA): msg[pos[e]] = bf16((feat[src[e]] @ W[rel]) * norm[e])
// v5: each block = TPB(4) consecutive 64-edge tiles of ONE relation.
//  - B staged in LDS once per block (was once per tile): B L2 traffic /4
//  - 2-deep software pipeline, NO in-loop barriers: src fetched 2 tiles
//    ahead, A-frags/norm/pos 1 tile ahead -> gather latency hidden under
//    the previous tile's MFMA+store (round-4 limiter: 58.5us vs 32us BW
//    floor, occupancy 36%, nothing saturated = latency-bound).
//  - D-bounce through dedicated D_lds; each wave re-reads only ITS OWN 16
//    rows -> wave-internal lgkm ordering, no __syncthreads needed.
// ---------------------------------------------------------------------------
__global__ __launch_bounds__(256) void edge_gemm_mfma(
    const float* __restrict__ feat, const __bf16* __restrict__ featb,
    const __bf16* __restrict__ Wp, const float* __restrict__ norm,
    const int* __restrict__ src, const int* __restrict__ pos,
    unsigned short* __restrict__ msg, int e_lo) {
  __shared__ __bf16 B_lds[IN_FEAT * OUT_FEAT];   // 32 KB, k-packed
  __shared__ __bf16 D_lds[64 * 136];             // 17.4 KB D-bounce
  int t = threadIdx.x;
  long base = (long)e_lo + (long)blockIdx.x * (64 * TPB);
  int rel = (int)(base >> 14);                   // 64*TPB divides 16384
  const __bf16* Wr = Wp + (long)rel * (IN_FEAT * OUT_FEAT);

  // stage B once per block (sequential, L2-hot across 64 blocks/rel)
  {
    const uint4* Wr4 = (const uint4*)Wr;
    uint4* B4 = (uint4*)B_lds;
#pragma unroll
    for (int j = 0; j < 8; ++j) B4[t + j * 256] = Wr4[t + j * 256];
  }

  int wave = t >> 6, lane = t & 63;
  int m16 = lane & 15, quad = lane >> 4;

  bf16x8 aA[4], aB[4];
  float nmA[4], nmB[4];
  int poA[4], poB[4];
  int srow0, srow1;

#define LOAD_SROW(dst, it) (dst) = src[base + (it) * 64 + wave * 16 + m16]

#define LOAD_TILE(aX, nmX, poX, it, srowX)                                   \
  do {                                                                       \
    if (featb) {                                                             \
      const __bf16* ap = featb + (long)(srowX)*128 + quad * 8;               \
      _Pragma("unroll") for (int ks = 0; ks < 4; ++ks)                       \
          aX[ks] = *(const bf16x8*)(ap + ks * 32);                           \
    } else {                                                                 \
      const float* fp = feat + (long)(srowX)*128 + quad * 8;                 \
      _Pragma("unroll") for (int ks = 0; ks < 4; ++ks) {                     \
        float4 lo = *(const float4*)(fp + ks * 32);                          \
        float4 hi = *(const float4*)(fp + ks * 32 + 4);                      \
        __bf16 tb[8] = {(__bf16)lo.x, (__bf16)lo.y, (__bf16)lo.z,            \
                        (__bf16)lo.w, (__bf16)hi.x, (__bf16)hi.y,            \
                        (__bf16)hi.z, (__bf16)hi.w};                         \
        aX[ks] = *(bf16x8*)tb;                                               \
      }                                                                      \
    }                                                                        \
    _Pragma("unroll") for (int r = 0; r < 4; ++r)                            \
        nmX[r] = norm[base + (it) * 64 + wave * 16 + quad * 4 + r];          \
    _Pragma("unroll") for (int i = 0; i < 4; ++i)                            \
        poX[i] = pos[base + (it) * 64 + wave * 16 + i * 4 + quad];           \
  } while (0)

#define COMPUTE_TILE(aX, nmX, poX)                                           \
  do {                                                                       \
    floatx4 acc[8];                                                          \
    _Pragma("unroll") for (int nt = 0; nt < 8; ++nt)                         \
        acc[nt] = (floatx4){0.f, 0.f, 0.f, 0.f};                             \
    _Pragma("unroll") for (int ks = 0; ks < 4; ++ks) {                       \
      int kp = ks * 4 + quad;                                                \
      _Pragma("unroll") for (int nt = 0; nt < 8; ++nt) {                     \
        bf16x8 b = *(const bf16x8*)(B_lds + (kp * 128 + nt * 16 + m16) * 8); \
        acc[nt] =                                                            \
            __builtin_amdgcn_mfma_f32_16x16x32_bf16(aX[ks], b, acc[nt],      \
                                                    0, 0, 0);                \
      }                                                                      \
    }                                                                        \
    _Pragma("unroll") for (int r = 0; r < 4; ++r) {                          \
      int erow = wave * 16 + quad * 4 + r;                                   \
      _Pragma("unroll") for (int nt = 0; nt < 8; ++nt)                       \
          D_lds[erow * 136 + nt * 16 + m16] = (__bf16)(acc[nt][r] * nmX[r]); \
    }                                                                        \
    __builtin_amdgcn_wave_barrier();                                         \
    _Pragma("unroll") for (int i = 0; i < 4; ++i) {                          \
      int row = wave * 16 + i * 4 + quad;                                    \
      uint4 v = *(const uint4*)&D_lds[row * 136 + m16 * 8];                  \
      *(uint4*)(msg + (long)poX[i] * 128 + m16 * 8) = v;                     \
    }                                                                        \
    __builtin_amdgcn_wave_barrier();                                         \
  } while (0)

  // -------- software pipeline: src 2 ahead, tile-data 1 ahead --------
  LOAD_SROW(srow0, 0);
  LOAD_SROW(srow1, 1);
  LOAD_TILE(aA, nmA, poA, 0, srow0);
  __syncthreads();  // B_lds ready

  LOAD_TILE(aB, nmB, poB, 1, srow1);
  LOAD_SROW(srow0, 2);
  COMPUTE_TILE(aA, nmA, poA);       // tile 0

  LOAD_TILE(aA, nmA, poA, 2, srow0);
  LOAD_SROW(srow1, 3);
  COMPUTE_TILE(aB, nmB, poB);       // tile 1

  LOAD_TILE(aB, nmB, poB, 3, srow1);
  COMPUTE_TILE(aA, nmA, poA);       // tile 2

  COMPUTE_TILE(aB, nmB, poB);       // tile 3

#undef LOAD_SROW
#undef LOAD_TILE
#undef COMPUTE_TILE
}

// ---------------------------------------------------------------------------
// Phase B: CSR gather, 4 msg rows / iter (uint4/lane = 1KB per wave-iter).
// quarter q=lane>>4 picks the row, c8=lane&15 picks 8 consecutive cols.
// Cross-quarter reduce via 2x shfl_xor; msg reads sequential (CSR order).
// ---------------------------------------------------------------------------
__global__ __launch_bounds__(256) void gather_csr_kernel(
    const unsigned short* __restrict__ msg, const int* __restrict__ rowc,
    float* __restrict__ out, int do_relu) {
  int wave = threadIdx.x >> 6, lane = threadIdx.x & 63;
  int n = blockIdx.x * 4 + wave;
  if (n >= N_NODES) return;
  int beg = rowc[n], end = rowc[n + 1];
  if (!do_relu && beg == end) return;
  int q = lane >> 4;
  int c8 = lane & 15;
  float s[8] = {0.f, 0.f, 0.f, 0.f, 0.f, 0.f, 0.f, 0.f};
  for (int j = beg; j < end; j += 4) {
    int jr = j + q;
    if (jr < end) {
      uint4 m = *(const uint4*)(msg + (long)jr * 128 + c8 * 8);
      s[0] += __uint_as_float(m.x << 16);
      s[1] += __uint_as_float(m.x & 0xFFFF0000u);
      s[2] += __uint_as_float(m.y << 16);
      s[3] += __uint_as_float(m.y & 0xFFFF0000u);
      s[4] += __uint_as_float(m.z << 16);
      s[5] += __uint_as_float(m.z & 0xFFFF0000u);
      s[6] += __uint_as_float(m.w << 16);
      s[7] += __uint_as_float(m.w & 0xFFFF0000u);
    }
  }
#pragma unroll
  for (int k = 0; k < 8; ++k) {
    s[k] += __shfl_xor(s[k], 16);
    s[k] += __shfl_xor(s[k], 32);
  }
  if (q == 0) {
    float4 o0 = ((float4*)out)[(long)n * 32 + c8 * 2];
    float4 o1 = ((float4*)out)[(long)n * 32 + c8 * 2 + 1];
    o0.x += s[0]; o0.y += s[1]; o0.z += s[2]; o0.w += s[3];
    o1.x += s[4]; o1.y += s[5]; o1.z += s[6]; o1.w += s[7];
    if (do_relu) {
      o0.x = fmaxf(o0.x, 0.f); o0.y = fmaxf(o0.y, 0.f);
      o0.z = fmaxf(o0.z, 0.f); o0.w = fmaxf(o0.w, 0.f);
      o1.x = fmaxf(o1.x, 0.f); o1.y = fmaxf(o1.y, 0.f);
      o1.z = fmaxf(o1.z, 0.f); o1.w = fmaxf(o1.w, 0.f);
    }
    ((float4*)out)[(long)n * 32 + c8 * 2] = o0;
    ((float4*)out)[(long)n * 32 + c8 * 2 + 1] = o1;
  }
}

// ---------------------------------------------------------------------------
// Fallback (tiny ws): fp32 init + GEMM + atomic scatter + relu
// ---------------------------------------------------------------------------
__global__ __launch_bounds__(256) void init_out_f32_kernel(
    const float* __restrict__ feat, const float* __restrict__ loop_w,
    const float* __restrict__ bias, float* __restrict__ out) {
  __shared__ float4 A4[64][32];
  int t = threadIdx.x;
  long base = (long)blockIdx.x * 64;
#pragma unroll
  for (int j = 0; j < 8; ++j) {
    int idx = t + j * 256;
    int e = idx >> 5, k4 = idx & 31;
    long n = base + e;
    float4 v = make_float4(0.f, 0.f, 0.f, 0.f);
    if (n < N_NODES) v = ((const float4*)feat)[n * 32 + k4];
    A4[e][k4] = v;
  }
  __syncthreads();
  int og = t & 31, eg = t >> 5;
  float acc[8][4];
#pragma unroll
  for (int j = 0; j < 8; ++j)
#pragma unroll
    for (int d = 0; d < 4; ++d) acc[j][d] = 0.f;
  const float4* W4 = (const float4*)loop_w;
  for (int k4 = 0; k4 < 32; ++k4) {
    float4 a[8];
#pragma unroll
    for (int j = 0; j < 8; ++j) a[j] = A4[eg * 8 + j][k4];
#pragma unroll
    for (int d = 0; d < 4; ++d) {
      float4 w = W4[(k4 * 4 + d) * 32 + og];
#pragma unroll
      for (int j = 0; j < 8; ++j) {
        float av = ((const float*)&a[j])[d];
        acc[j][0] += av * w.x;
        acc[j][1] += av * w.y;
        acc[j][2] += av * w.z;
        acc[j][3] += av * w.w;
      }
    }
  }
  float4 b = ((const float4*)bias)[og];
#pragma unroll
  for (int j = 0; j < 8; ++j) {
    long n = base + eg * 8 + j;
    if (n < N_NODES) {
      float4 v = make_float4(acc[j][0] + b.x, acc[j][1] + b.y,
                             acc[j][2] + b.z, acc[j][3] + b.w);
      ((float4*)out)[n * 32 + og] = v;
    }
  }
}

__global__ __launch_bounds__(256) void edge_msg_atomic_kernel(
    const float* __restrict__ feat, const float* __restrict__ W,
    const float* __restrict__ norm, const int* __restrict__ src,
    const int* __restrict__ dst, float* __restrict__ out) {
  __shared__ float4 A4[64][32];
  __shared__ int s_src[64];
  __shared__ int s_dst[64];
  __shared__ float s_norm[64];
  int t = threadIdx.x;
  long base = (long)blockIdx.x * 64;
  int rel = blockIdx.x >> 8;
  const float4* Wr4 = (const float4*)(W + (long)rel * IN_FEAT * OUT_FEAT);
  if (t < 64) {
    s_src[t] = src[base + t];
    s_dst[t] = dst[base + t];
    s_norm[t] = norm[base + t];
  }
  __syncthreads();
#pragma unroll
  for (int j = 0; j < 8; ++j) {
    int idx = t + j * 256;
    int e = idx >> 5, k4 = idx & 31;
    A4[e][k4] = ((const float4*)feat)[(long)s_src[e] * 32 + k4];
  }
  __syncthreads();
  int og = t & 31, eg = t >> 5;
  float acc[8][4];
#pragma unroll
  for (int j = 0; j < 8; ++j)
#pragma unroll
    for (int d = 0; d < 4; ++d) acc[j][d] = 0.f;
  for (int k4 = 0; k4 < 32; ++k4) {
    float4 a[8];
#pragma unroll
    for (int j = 0; j < 8; ++j) a[j] = A4[eg * 8 + j][k4];
#pragma unroll
    for (int d = 0; d < 4; ++d) {
      float4 w = Wr4[(k4 * 4 + d) * 32 + og];
#pragma unroll
      for (int j = 0; j < 8; ++j) {
        float av = ((const float*)&a[j])[d];
        acc[j][0] += av * w.x;
        acc[j][1] += av * w.y;
        acc[j][2] += av * w.z;
        acc[j][3] += av * w.w;
      }
    }
  }
#pragma unroll
  for (int j = 0; j < 8; ++j) {
    int e = eg * 8 + j;
    float nm = s_norm[e];
    float* orow = out + (long)s_dst[e] * OUT_FEAT + og * 4;
#pragma unroll
    for (int d = 0; d < 4; ++d) atomicAdd(orow + d, acc[j][d] * nm);
  }
}

__global__ __launch_bounds__(256) void relu_kernel(float* __restrict__ out) {
  int idx = blockIdx.x * 256 + threadIdx.x;
  float4 v = ((const float4*)out)[idx];
  v.x = fmaxf(v.x, 0.f);
  v.y = fmaxf(v.y, 0.f);
  v.z = fmaxf(v.z, 0.f);
  v.w = fmaxf(v.w, 0.f);
  ((float4*)out)[idx] = v;
}

extern "C" void kernel_launch(void* const* d_in, const int* in_sizes, int n_in,
                              void* d_out, int out_size, void* d_ws, size_t ws_size,
                              hipStream_t stream) {
  const float* feat   = (const float*)d_in[0];
  const float* weight = (const float*)d_in[1];
  const float* w_comp = (const float*)d_in[2];
  const float* h_bias = (const float*)d_in[3];
  const float* loop_w = (const float*)d_in[4];
  const float* norm   = (const float*)d_in[5];
  const int*   src    = (const int*)d_in[6];
  const int*   dst    = (const int*)d_in[7];
  float* out = (float*)d_out;

  const size_t SZ_WP  = (size_t)NUM_RELS * IN_FEAT * OUT_FEAT * 2;  // 2 MB
  const size_t SZ_LP  = (size_t)IN_FEAT * OUT_FEAT * 2;             // 32 KB
  const size_t SZ_FB  = (size_t)N_NODES * IN_FEAT * 2;              // 25.6 MB
  const size_t SZ_POS = (size_t)E_TOTAL * 4;                        // 4 MB

  // Config ladder: prefer fewest out-RMW passes, then the bf16-feat copy
  // (halves Phase-A gather traffic). Rounds 1-4 resolved (32,1).
  int CH = 0, FB = 0;
  {
    const int chs[10] = {64, 32, 32, 16, 16, 8, 8, 4, 4, 0};
    const int fbs[10] = { 1,  1,  0,  1,  0, 1, 0, 1, 0, 0};
    for (int i = 0; i < 9 && CH == 0; ++i) {
      int ch = chs[i], fb = fbs[i], nc = NUM_RELS / ch;
      size_t need = SZ_WP + SZ_LP + (fb ? SZ_FB : 0) + SZ_POS +
                    2 * (size_t)nc * N_PAD * 4 + 2 * (size_t)nc * NBLK * 4 +
                    (size_t)ch * EDGES_PER_REL * OUT_FEAT * 2;
      if (ws_size >= need) { CH = ch; FB = fb; }
    }
  }

  if (CH > 0) {
    const int NC = NUM_RELS / CH;
    const int chunk_edges = CH * EDGES_PER_REL;
    int cshift = 14;
    for (int x = CH; x > 1; x >>= 1) ++cshift;

    char* p = (char*)d_ws;
    __bf16* Wp = (__bf16*)p;                  p += SZ_WP;
    __bf16* Lp = (__bf16*)p;                  p += SZ_LP;
    __bf16* featb = nullptr;
    if (FB) { featb = (__bf16*)p;             p += SZ_FB; }
    int* pos  = (int*)p;                      p += SZ_POS;
    int* cnt8 = (int*)p;                      p += (size_t)NC * N_PAD * 4;
    int* row8 = (int*)p;                      p += (size_t)NC * N_PAD * 4;
    int* bsum = (int*)p;                      p += (size_t)NC * NBLK * 4;
    int* boff = (int*)p;                      p += (size_t)NC * NBLK * 4;
    unsigned short* msg = (unsigned short*)p;

    hipLaunchKernelGGL(compose_all_bf16_kernel,
                       dim3((NUM_RELS * 16384 + 16384) / 256), dim3(256), 0,
                       stream, weight, w_comp, loop_w, Wp, Lp);
    hipLaunchKernelGGL(init_out_mfma, dim3((N_NODES + 63) / 64), dim3(256), 0,
                       stream, feat, featb, Lp, h_bias, out);
    hipLaunchKernelGGL(zero_kernel, dim3(NC * NBLK), dim3(256), 0, stream, cnt8);
    hipLaunchKernelGGL(hist8_kernel, dim3(E_TOTAL / 256), dim3(256), 0, stream,
                       dst, cnt8, cshift);
    hipLaunchKernelGGL(scan1_kernel, dim3(NC * NBLK), dim3(256), 0, stream,
                       cnt8, row8, bsum);
    hipLaunchKernelGGL(scan2_kernel, dim3(NC), dim3(512), 0, stream, bsum, boff);
    hipLaunchKernelGGL(scan3_kernel, dim3(NC * NBLK), dim3(256), 0, stream,
                       row8, boff, cnt8);
    hipLaunchKernelGGL(scatter_pos_kernel, dim3(E_TOTAL / 256), dim3(256), 0,
                       stream, dst, cnt8, pos, cshift);

    for (int c = 0; c < NC; ++c) {
      hipLaunchKernelGGL(edge_gemm_mfma, dim3(chunk_edges / (64 * TPB)),
                         dim3(256), 0, stream, feat, featb, Wp, norm, src, pos,
                         msg, c * chunk_edges);
      hipLaunchKernelGGL(gather_csr_kernel, dim3((N_NODES + 3) / 4), dim3(256),
                         0, stream, msg, row8 + (size_t)c * N_PAD, out,
                         (c == NC - 1) ? 1 : 0);
    }
  } else {
    float* W = (float*)d_ws;
    hipLaunchKernelGGL(init_out_f32_kernel, dim3((N_NODES + 63) / 64),
                       dim3(256), 0, stream, feat, loop_w, h_bias, out);
    hipLaunchKernelGGL(compose_w_f32_kernel, dim3(NUM_RELS * 16384 / 256),
                       dim3(256), 0, stream, weight, w_comp, W);
    hipLaunchKernelGGL(edge_msg_atomic_kernel, dim3(E_TOTAL / 64), dim3(256), 0,
                       stream, feat, W, norm, src, dst, out);
    hipLaunchKernelGGL(relu_kernel, dim3((N_NODES * OUT_FEAT / 4) / 256),
                       dim3(256), 0, stream, out);
  }
}

// Round 6
// 403.294 us; speedup vs baseline: 1.1447x; 1.0459x over previous
//
#include <hip/hip_runtime.h>

#define N_NODES 100000
#define N_PAD 100352          // 392 * 256
#define NBLK 392
#define IN_FEAT 128
#define OUT_FEAT 128
#define NUM_RELS 64
#define EDGES_PER_REL 16384
#define NUM_BASES 16
#define E_TOTAL (NUM_RELS * EDGES_PER_REL)
#define TPB 4                 // 64-edge tiles per block in edge_gemm (256 edges)

typedef __bf16 bf16x8 __attribute__((ext_vector_type(8)));
typedef float floatx4 __attribute__((ext_vector_type(4)));

// ---------------------------------------------------------------------------
// Fused W composition (bf16 k-packed Wp[r][kp][n][j]) + loop_weight pack.
// ---------------------------------------------------------------------------
__global__ __launch_bounds__(256) void compose_all_bf16_kernel(
    const float* __restrict__ weight, const float* __restrict__ w_comp,
    const float* __restrict__ loop_w, __bf16* __restrict__ Wp,
    __bf16* __restrict__ Lp) {
  int gid = blockIdx.x * 256 + threadIdx.x;
  if (gid < NUM_RELS * 16384) {
    int r = gid >> 14;
    int off = gid & 16383;
    int j = off & 7, n = (off >> 3) & 127, kp = off >> 10;
    int k = kp * 8 + j;
    const float* wc = w_comp + r * NUM_BASES;
    float acc = 0.f;
#pragma unroll
    for (int b = 0; b < NUM_BASES; ++b)
      acc += wc[b] * weight[b * 16384 + k * 128 + n];
    Wp[gid] = (__bf16)acc;
  } else {
    int idx = gid - NUM_RELS * 16384;          // 16384 loop-weight elems
    int j = idx & 7, n = (idx >> 3) & 127, kp = idx >> 10;
    Lp[idx] = (__bf16)loop_w[(kp * 8 + j) * 128 + n];
  }
}

__global__ __launch_bounds__(256) void compose_w_f32_kernel(
    const float* __restrict__ weight, const float* __restrict__ w_comp,
    float* __restrict__ W) {
  int idx = blockIdx.x * 256 + threadIdx.x;
  int r = idx >> 14;
  int io = idx & 16383;
  const float* wc = w_comp + r * NUM_BASES;
  float acc = 0.f;
#pragma unroll
  for (int b = 0; b < NUM_BASES; ++b)
    acc += wc[b] * weight[b * 16384 + io];
  W[idx] = acc;
}

// ---------------------------------------------------------------------------
// out[n] = h_bias + feat[n] @ loop_weight   (MFMA bf16, 64 nodes / block)
// Also PRODUCES featb (bf16 feat copy) as a side output when non-null.
// ---------------------------------------------------------------------------
__global__ __launch_bounds__(256) void init_out_mfma(
    const float* __restrict__ feat, __bf16* __restrict__ featb,
    const __bf16* __restrict__ Lp, const float* __restrict__ bias,
    float* __restrict__ out) {
  __shared__ __bf16 A_lds[64 * 136];
  int t = threadIdx.x;
  long base = (long)blockIdx.x * 64;
#pragma unroll
  for (int j = 0; j < 8; ++j) {
    int idx = t + j * 256;
    int e = idx >> 5, k4 = idx & 31;
    long n = base + e;
    float4 v = make_float4(0.f, 0.f, 0.f, 0.f);
    bool ok = (n < N_NODES);
    if (ok) v = ((const float4*)feat)[n * 32 + k4];
    __bf16 tb[4] = {(__bf16)v.x, (__bf16)v.y, (__bf16)v.z, (__bf16)v.w};
    *(ushort4*)&A_lds[e * 136 + k4 * 4] = *(ushort4*)tb;
    if (featb && ok)
      *(ushort4*)(featb + n * 128 + k4 * 4) = *(ushort4*)tb;
  }
  __syncthreads();

  int wave = t >> 6, lane = t & 63;
  int m16 = lane & 15, quad = lane >> 4;
  floatx4 acc[8];
#pragma unroll
  for (int nt = 0; nt < 8; ++nt) acc[nt] = (floatx4){0.f, 0.f, 0.f, 0.f};

  const __bf16* a_base = &A_lds[(wave * 16 + m16) * 136 + quad * 8];
#pragma unroll
  for (int ks = 0; ks < 4; ++ks) {
    bf16x8 a = *(const bf16x8*)(a_base + ks * 32);
    int kp = ks * 4 + quad;
#pragma unroll
    for (int nt = 0; nt < 8; ++nt) {
      bf16x8 b = *(const bf16x8*)(Lp + (kp * 128 + nt * 16 + m16) * 8);
      acc[nt] = __builtin_amdgcn_mfma_f32_16x16x32_bf16(a, b, acc[nt], 0, 0, 0);
    }
  }

  float bv[8];
#pragma unroll
  for (int nt = 0; nt < 8; ++nt) bv[nt] = bias[nt * 16 + m16];
#pragma unroll
  for (int r = 0; r < 4; ++r) {
    long n = base + wave * 16 + quad * 4 + r;
    if (n < N_NODES) {
#pragma unroll
      for (int nt = 0; nt < 8; ++nt)
        out[n * 128 + nt * 16 + m16] = acc[nt][r] + bv[nt];
    }
  }
}

// ---------------------------------------------------------------------------
// Per-chunk CSR build (scatter_pos removed in v6 — positions are claimed
// on-the-fly in edge_gemm via atomicAdd on fill)
// ---------------------------------------------------------------------------
__global__ __launch_bounds__(256) void zero_kernel(int* __restrict__ p) {
  p[blockIdx.x * 256 + threadIdx.x] = 0;
}

__global__ __launch_bounds__(256) void hist8_kernel(
    const int* __restrict__ dst, int* __restrict__ cnt8, int cshift) {
  int e = blockIdx.x * 256 + threadIdx.x;
  int c = e >> cshift;
  atomicAdd(&cnt8[c * N_PAD + dst[e]], 1);
}

__global__ __launch_bounds__(256) void scan1_kernel(
    const int* __restrict__ cnt, int* __restrict__ row,
    int* __restrict__ bsum) {
  __shared__ int s[256];
  int t = threadIdx.x;
  int idx = blockIdx.x * 256 + t;
  int v = cnt[idx];
  s[t] = v;
  __syncthreads();
  for (int o = 1; o < 256; o <<= 1) {
    int x = (t >= o) ? s[t - o] : 0;
    __syncthreads();
    s[t] += x;
    __syncthreads();
  }
  row[idx] = s[t] - v;
  if (t == 255) bsum[blockIdx.x] = s[t];
}

__global__ __launch_bounds__(512) void scan2_kernel(
    const int* __restrict__ bsum, int* __restrict__ boff) {
  __shared__ int s[512];
  int t = threadIdx.x;
  int v = (t < NBLK) ? bsum[blockIdx.x * NBLK + t] : 0;
  s[t] = v;
  __syncthreads();
  for (int o = 1; o < 512; o <<= 1) {
    int x = (t >= o) ? s[t - o] : 0;
    __syncthreads();
    s[t] += x;
    __syncthreads();
  }
  if (t < NBLK) boff[blockIdx.x * NBLK + t] = s[t] - v;
}

__global__ __launch_bounds__(256) void scan3_kernel(
    int* __restrict__ row, const int* __restrict__ boff,
    int* __restrict__ fill) {
  int idx = blockIdx.x * 256 + threadIdx.x;
  int v = row[idx] + boff[blockIdx.x];
  row[idx] = v;
  fill[idx] = v;
}

// ---------------------------------------------------------------------------
// Phase A (MFMA): msg[po] = bf16((feat[src[e]] @ W[rel]) * norm[e])
// v6: CSR slot po claimed on-the-fly: lanes 0..15 of each wave do
// atomicAdd(&fill[dst[e]],1) and __shfl-broadcast — removes the
// scatter_pos kernel + pos array. Within-node msg order becomes
// nondeterministic; Phase-B sum is order-insensitive within tolerance.
// Block = TPB(4) consecutive 64-edge tiles of ONE relation; B staged once;
// 2-deep pipeline, no in-loop barriers (round-5 structure).
// ---------------------------------------------------------------------------
__global__ __launch_bounds__(256) void edge_gemm_mfma(
    const float* __restrict__ feat, const __bf16* __restrict__ featb,
    const __bf16* __restrict__ Wp, const float* __restrict__ norm,
    const int* __restrict__ src, const int* __restrict__ dst,
    int* __restrict__ fill, unsigned short* __restrict__ msg, int e_lo) {
  __shared__ __bf16 B_lds[IN_FEAT * OUT_FEAT];   // 32 KB, k-packed
  __shared__ __bf16 D_lds[64 * 136];             // 17.4 KB D-bounce
  int t = threadIdx.x;
  long base = (long)e_lo + (long)blockIdx.x * (64 * TPB);
  int rel = (int)(base >> 14);                   // 64*TPB divides 16384
  const __bf16* Wr = Wp + (long)rel * (IN_FEAT * OUT_FEAT);

  // stage B once per block (sequential, L2-hot across 64 blocks/rel)
  {
    const uint4* Wr4 = (const uint4*)Wr;
    uint4* B4 = (uint4*)B_lds;
#pragma unroll
    for (int j = 0; j < 8; ++j) B4[t + j * 256] = Wr4[t + j * 256];
  }

  int wave = t >> 6, lane = t & 63;
  int m16 = lane & 15, quad = lane >> 4;

  bf16x8 aA[4], aB[4];
  float nmA[4], nmB[4];
  int poA[4], poB[4];
  int srow0, srow1;

#define LOAD_SROW(dstv, it) (dstv) = src[base + (it) * 64 + wave * 16 + m16]

#define LOAD_TILE(aX, nmX, poX, it, srowX)                                   \
  do {                                                                       \
    if (featb) {                                                             \
      const __bf16* ap = featb + (long)(srowX)*128 + quad * 8;               \
      _Pragma("unroll") for (int ks = 0; ks < 4; ++ks)                       \
          aX[ks] = *(const bf16x8*)(ap + ks * 32);                           \
    } else {                                                                 \
      const float* fp = feat + (long)(srowX)*128 + quad * 8;                 \
      _Pragma("unroll") for (int ks = 0; ks < 4; ++ks) {                     \
        float4 lo = *(const float4*)(fp + ks * 32);                          \
        float4 hi = *(const float4*)(fp + ks * 32 + 4);                      \
        __bf16 tb[8] = {(__bf16)lo.x, (__bf16)lo.y, (__bf16)lo.z,            \
                        (__bf16)lo.w, (__bf16)hi.x, (__bf16)hi.y,            \
                        (__bf16)hi.z, (__bf16)hi.w};                         \
        aX[ks] = *(bf16x8*)tb;                                               \
      }                                                                      \
    }                                                                        \
    _Pragma("unroll") for (int r = 0; r < 4; ++r)                            \
        nmX[r] = norm[base + (it) * 64 + wave * 16 + quad * 4 + r];          \
    {                                                                        \
      int poMine = 0;                                                        \
      if (lane < 16)                                                         \
        poMine =                                                             \
            atomicAdd(&fill[dst[base + (it) * 64 + wave * 16 + lane]], 1);   \
      _Pragma("unroll") for (int i = 0; i < 4; ++i)                          \
          poX[i] = __shfl(poMine, i * 4 + quad);                             \
    }                                                                        \
  } while (0)

#define COMPUTE_TILE(aX, nmX, poX)                                           \
  do {                                                                       \
    floatx4 acc[8];                                                          \
    _Pragma("unroll") for (int nt = 0; nt < 8; ++nt)                         \
        acc[nt] = (floatx4){0.f, 0.f, 0.f, 0.f};                             \
    _Pragma("unroll") for (int ks = 0; ks < 4; ++ks) {                       \
      int kp = ks * 4 + quad;                                                \
      _Pragma("unroll") for (int nt = 0; nt < 8; ++nt) {                     \
        bf16x8 b = *(const bf16x8*)(B_lds + (kp * 128 + nt * 16 + m16) * 8); \
        acc[nt] =                                                            \
            __builtin_amdgcn_mfma_f32_16x16x32_bf16(aX[ks], b, acc[nt],      \
                                                    0, 0, 0);                \
      }                                                                      \
    }                                                                        \
    _Pragma("unroll") for (int r = 0; r < 4; ++r) {                          \
      int erow = wave * 16 + quad * 4 + r;                                   \
      _Pragma("unroll") for (int nt = 0; nt < 8; ++nt)                       \
          D_lds[erow * 136 + nt * 16 + m16] = (__bf16)(acc[nt][r] * nmX[r]); \
    }                                                                        \
    __builtin_amdgcn_wave_barrier();                                         \
    _Pragma("unroll") for (int i = 0; i < 4; ++i) {                          \
      int row = wave * 16 + i * 4 + quad;                                    \
      uint4 v = *(const uint4*)&D_lds[row * 136 + m16 * 8];                  \
      *(uint4*)(msg + (long)poX[i] * 128 + m16 * 8) = v;                     \
    }                                                                        \
    __builtin_amdgcn_wave_barrier();                                         \
  } while (0)

  // -------- software pipeline: src 2 ahead, tile-data 1 ahead --------
  LOAD_SROW(srow0, 0);
  LOAD_SROW(srow1, 1);
  LOAD_TILE(aA, nmA, poA, 0, srow0);
  __syncthreads();  // B_lds ready

  LOAD_TILE(aB, nmB, poB, 1, srow1);
  LOAD_SROW(srow0, 2);
  COMPUTE_TILE(aA, nmA, poA);       // tile 0

  LOAD_TILE(aA, nmA, poA, 2, srow0);
  LOAD_SROW(srow1, 3);
  COMPUTE_TILE(aB, nmB, poB);       // tile 1

  LOAD_TILE(aB, nmB, poB, 3, srow1);
  COMPUTE_TILE(aA, nmA, poA);       // tile 2

  COMPUTE_TILE(aB, nmB, poB);       // tile 3

#undef LOAD_SROW
#undef LOAD_TILE
#undef COMPUTE_TILE
}

// ---------------------------------------------------------------------------
// Phase B: CSR gather, 4 msg rows / iter (uint4/lane = 1KB per wave-iter).
// ---------------------------------------------------------------------------
__global__ __launch_bounds__(256) void gather_csr_kernel(
    const unsigned short* __restrict__ msg, const int* __restrict__ rowc,
    float* __restrict__ out, int do_relu) {
  int wave = threadIdx.x >> 6, lane = threadIdx.x & 63;
  int n = blockIdx.x * 4 + wave;
  if (n >= N_NODES) return;
  int beg = rowc[n], end = rowc[n + 1];
  if (!do_relu && beg == end) return;
  int q = lane >> 4;
  int c8 = lane & 15;
  float s[8] = {0.f, 0.f, 0.f, 0.f, 0.f, 0.f, 0.f, 0.f};
  for (int j = beg; j < end; j += 4) {
    int jr = j + q;
    if (jr < end) {
      uint4 m = *(const uint4*)(msg + (long)jr * 128 + c8 * 8);
      s[0] += __uint_as_float(m.x << 16);
      s[1] += __uint_as_float(m.x & 0xFFFF0000u);
      s[2] += __uint_as_float(m.y << 16);
      s[3] += __uint_as_float(m.y & 0xFFFF0000u);
      s[4] += __uint_as_float(m.z << 16);
      s[5] += __uint_as_float(m.z & 0xFFFF0000u);
      s[6] += __uint_as_float(m.w << 16);
      s[7] += __uint_as_float(m.w & 0xFFFF0000u);
    }
  }
#pragma unroll
  for (int k = 0; k < 8; ++k) {
    s[k] += __shfl_xor(s[k], 16);
    s[k] += __shfl_xor(s[k], 32);
  }
  if (q == 0) {
    float4 o0 = ((float4*)out)[(long)n * 32 + c8 * 2];
    float4 o1 = ((float4*)out)[(long)n * 32 + c8 * 2 + 1];
    o0.x += s[0]; o0.y += s[1]; o0.z += s[2]; o0.w += s[3];
    o1.x += s[4]; o1.y += s[5]; o1.z += s[6]; o1.w += s[7];
    if (do_relu) {
      o0.x = fmaxf(o0.x, 0.f); o0.y = fmaxf(o0.y, 0.f);
      o0.z = fmaxf(o0.z, 0.f); o0.w = fmaxf(o0.w, 0.f);
      o1.x = fmaxf(o1.x, 0.f); o1.y = fmaxf(o1.y, 0.f);
      o1.z = fmaxf(o1.z, 0.f); o1.w = fmaxf(o1.w, 0.f);
    }
    ((float4*)out)[(long)n * 32 + c8 * 2] = o0;
    ((float4*)out)[(long)n * 32 + c8 * 2 + 1] = o1;
  }
}

// ---------------------------------------------------------------------------
// Fallback (tiny ws): fp32 init + GEMM + atomic scatter + relu
// ---------------------------------------------------------------------------
__global__ __launch_bounds__(256) void init_out_f32_kernel(
    const float* __restrict__ feat, const float* __restrict__ loop_w,
    const float* __restrict__ bias, float* __restrict__ out) {
  __shared__ float4 A4[64][32];
  int t = threadIdx.x;
  long base = (long)blockIdx.x * 64;
#pragma unroll
  for (int j = 0; j < 8; ++j) {
    int idx = t + j * 256;
    int e = idx >> 5, k4 = idx & 31;
    long n = base + e;
    float4 v = make_float4(0.f, 0.f, 0.f, 0.f);
    if (n < N_NODES) v = ((const float4*)feat)[n * 32 + k4];
    A4[e][k4] = v;
  }
  __syncthreads();
  int og = t & 31, eg = t >> 5;
  float acc[8][4];
#pragma unroll
  for (int j = 0; j < 8; ++j)
#pragma unroll
    for (int d = 0; d < 4; ++d) acc[j][d] = 0.f;
  const float4* W4 = (const float4*)loop_w;
  for (int k4 = 0; k4 < 32; ++k4) {
    float4 a[8];
#pragma unroll
    for (int j = 0; j < 8; ++j) a[j] = A4[eg * 8 + j][k4];
#pragma unroll
    for (int d = 0; d < 4; ++d) {
      float4 w = W4[(k4 * 4 + d) * 32 + og];
#pragma unroll
      for (int j = 0; j < 8; ++j) {
        float av = ((const float*)&a[j])[d];
        acc[j][0] += av * w.x;
        acc[j][1] += av * w.y;
        acc[j][2] += av * w.z;
        acc[j][3] += av * w.w;
      }
    }
  }
  float4 b = ((const float4*)bias)[og];
#pragma unroll
  for (int j = 0; j < 8; ++j) {
    long n = base + eg * 8 + j;
    if (n < N_NODES) {
      float4 v = make_float4(acc[j][0] + b.x, acc[j][1] + b.y,
                             acc[j][2] + b.z, acc[j][3] + b.w);
      ((float4*)out)[n * 32 + og] = v;
    }
  }
}

__global__ __launch_bounds__(256) void edge_msg_atomic_kernel(
    const float* __restrict__ feat, const float* __restrict__ W,
    const float* __restrict__ norm, const int* __restrict__ src,
    const int* __restrict__ dst, float* __restrict__ out) {
  __shared__ float4 A4[64][32];
  __shared__ int s_src[64];
  __shared__ int s_dst[64];
  __shared__ float s_norm[64];
  int t = threadIdx.x;
  long base = (long)blockIdx.x * 64;
  int rel = blockIdx.x >> 8;
  const float4* Wr4 = (const float4*)(W + (long)rel * IN_FEAT * OUT_FEAT);
  if (t < 64) {
    s_src[t] = src[base + t];
    s_dst[t] = dst[base + t];
    s_norm[t] = norm[base + t];
  }
  __syncthreads();
#pragma unroll
  for (int j = 0; j < 8; ++j) {
    int idx = t + j * 256;
    int e = idx >> 5, k4 = idx & 31;
    A4[e][k4] = ((const float4*)feat)[(long)s_src[e] * 32 + k4];
  }
  __syncthreads();
  int og = t & 31, eg = t >> 5;
  float acc[8][4];
#pragma unroll
  for (int j = 0; j < 8; ++j)
#pragma unroll
    for (int d = 0; d < 4; ++d) acc[j][d] = 0.f;
  for (int k4 = 0; k4 < 32; ++k4) {
    float4 a[8];
#pragma unroll
    for (int j = 0; j < 8; ++j) a[j] = A4[eg * 8 + j][k4];
#pragma unroll
    for (int d = 0; d < 4; ++d) {
      float4 w = Wr4[(k4 * 4 + d) * 32 + og];
#pragma unroll
      for (int j = 0; j < 8; ++j) {
        float av = ((const float*)&a[j])[d];
        acc[j][0] += av * w.x;
        acc[j][1] += av * w.y;
        acc[j][2] += av * w.z;
        acc[j][3] += av * w.w;
      }
    }
  }
#pragma unroll
  for (int j = 0; j < 8; ++j) {
    int e = eg * 8 + j;
    float nm = s_norm[e];
    float* orow = out + (long)s_dst[e] * OUT_FEAT + og * 4;
#pragma unroll
    for (int d = 0; d < 4; ++d) atomicAdd(orow + d, acc[j][d] * nm);
  }
}

__global__ __launch_bounds__(256) void relu_kernel(float* __restrict__ out) {
  int idx = blockIdx.x * 256 + threadIdx.x;
  float4 v = ((const float4*)out)[idx];
  v.x = fmaxf(v.x, 0.f);
  v.y = fmaxf(v.y, 0.f);
  v.z = fmaxf(v.z, 0.f);
  v.w = fmaxf(v.w, 0.f);
  ((float4*)out)[idx] = v;
}

extern "C" void kernel_launch(void* const* d_in, const int* in_sizes, int n_in,
                              void* d_out, int out_size, void* d_ws, size_t ws_size,
                              hipStream_t stream) {
  const float* feat   = (const float*)d_in[0];
  const float* weight = (const float*)d_in[1];
  const float* w_comp = (const float*)d_in[2];
  const float* h_bias = (const float*)d_in[3];
  const float* loop_w = (const float*)d_in[4];
  const float* norm   = (const float*)d_in[5];
  const int*   src    = (const int*)d_in[6];
  const int*   dst    = (const int*)d_in[7];
  float* out = (float*)d_out;

  const size_t SZ_WP  = (size_t)NUM_RELS * IN_FEAT * OUT_FEAT * 2;  // 2 MB
  const size_t SZ_LP  = (size_t)IN_FEAT * OUT_FEAT * 2;             // 32 KB
  const size_t SZ_FB  = (size_t)N_NODES * IN_FEAT * 2;              // 25.6 MB

  // Config ladder: fewest out-RMW passes first, then the bf16-feat copy.
  // v6: pos array + scatter_pos dropped (on-the-fly atomic claim) -> the
  // 64-chunk configs are ~4-8 MB slimmer and may now fit the workspace.
  int CH = 0, FB = 0;
  {
    const int chs[11] = {64, 64, 32, 32, 16, 16, 8, 8, 4, 4, 0};
    const int fbs[11] = { 1,  0,  1,  0,  1,  0, 1, 0, 1, 0, 0};
    for (int i = 0; i < 10 && CH == 0; ++i) {
      int ch = chs[i], fb = fbs[i], nc = NUM_RELS / ch;
      size_t need = SZ_WP + SZ_LP + (fb ? SZ_FB : 0) +
                    2 * (size_t)nc * N_PAD * 4 + 2 * (size_t)nc * NBLK * 4 +
                    (size_t)ch * EDGES_PER_REL * OUT_FEAT * 2;
      if (ws_size >= need) { CH = ch; FB = fb; }
    }
  }

  if (CH > 0) {
    const int NC = NUM_RELS / CH;
    const int chunk_edges = CH * EDGES_PER_REL;
    int cshift = 14;
    for (int x = CH; x > 1; x >>= 1) ++cshift;

    char* p = (char*)d_ws;
    __bf16* Wp = (__bf16*)p;                  p += SZ_WP;
    __bf16* Lp = (__bf16*)p;                  p += SZ_LP;
    __bf16* featb = nullptr;
    if (FB) { featb = (__bf16*)p;             p += SZ_FB; }
    int* cnt8 = (int*)p;                      p += (size_t)NC * N_PAD * 4;
    int* row8 = (int*)p;                      p += (size_t)NC * N_PAD * 4;
    int* bsum = (int*)p;                      p += (size_t)NC * NBLK * 4;
    int* boff = (int*)p;                      p += (size_t)NC * NBLK * 4;
    unsigned short* msg = (unsigned short*)p;

    hipLaunchKernelGGL(compose_all_bf16_kernel,
                       dim3((NUM_RELS * 16384 + 16384) / 256), dim3(256), 0,
                       stream, weight, w_comp, loop_w, Wp, Lp);
    hipLaunchKernelGGL(init_out_mfma, dim3((N_NODES + 63) / 64), dim3(256), 0,
                       stream, feat, featb, Lp, h_bias, out);
    hipLaunchKernelGGL(zero_kernel, dim3(NC * NBLK), dim3(256), 0, stream, cnt8);
    hipLaunchKernelGGL(hist8_kernel, dim3(E_TOTAL / 256), dim3(256), 0, stream,
                       dst, cnt8, cshift);
    hipLaunchKernelGGL(scan1_kernel, dim3(NC * NBLK), dim3(256), 0, stream,
                       cnt8, row8, bsum);
    hipLaunchKernelGGL(scan2_kernel, dim3(NC), dim3(512), 0, stream, bsum, boff);
    hipLaunchKernelGGL(scan3_kernel, dim3(NC * NBLK), dim3(256), 0, stream,
                       row8, boff, cnt8);   // cnt8 becomes the fill cursors

    for (int c = 0; c < NC; ++c) {
      hipLaunchKernelGGL(edge_gemm_mfma, dim3(chunk_edges / (64 * TPB)),
                         dim3(256), 0, stream, feat, featb, Wp, norm, src, dst,
                         cnt8 + (size_t)c * N_PAD, msg, c * chunk_edges);
      hipLaunchKernelGGL(gather_csr_kernel, dim3((N_NODES + 3) / 4), dim3(256),
                         0, stream, msg, row8 + (size_t)c * N_PAD, out,
                         (c == NC - 1) ? 1 : 0);
    }
  } else {
    float* W = (float*)d_ws;
    hipLaunchKernelGGL(init_out_f32_kernel, dim3((N_NODES + 63) / 64),
                       dim3(256), 0, stream, feat, loop_w, h_bias, out);
    hipLaunchKernelGGL(compose_w_f32_kernel, dim3(NUM_RELS * 16384 / 256),
                       dim3(256), 0, stream, weight, w_comp, W);
    hipLaunchKernelGGL(edge_msg_atomic_kernel, dim3(E_TOTAL / 64), dim3(256), 0,
                       stream, feat, W, norm, src, dst, out);
    hipLaunchKernelGGL(relu_kernel, dim3((N_NODES * OUT_FEAT / 4) / 256),
                       dim3(256), 0, stream, out);
  }
}

// Round 7
// 392.071 us; speedup vs baseline: 1.1775x; 1.0286x over previous
//
#include <hip/hip_runtime.h>

#define N_NODES 100000
#define N_PAD 100352          // 392 * 256
#define NBLK 392
#define IN_FEAT 128
#define OUT_FEAT 128
#define NUM_RELS 64
#define EDGES_PER_REL 16384
#define NUM_BASES 16
#define E_TOTAL (NUM_RELS * EDGES_PER_REL)
#define TPB 4                 // 64-edge tiles per block in edge_gemm (256 edges)

typedef __bf16 bf16x8 __attribute__((ext_vector_type(8)));
typedef float floatx4 __attribute__((ext_vector_type(4)));

// ---------------------------------------------------------------------------
// Fused W composition (bf16 k-packed Wp[r][kp][n][j]) + loop_weight pack.
// ---------------------------------------------------------------------------
__global__ __launch_bounds__(256) void compose_all_bf16_kernel(
    const float* __restrict__ weight, const float* __restrict__ w_comp,
    const float* __restrict__ loop_w, __bf16* __restrict__ Wp,
    __bf16* __restrict__ Lp) {
  int gid = blockIdx.x * 256 + threadIdx.x;
  if (gid < NUM_RELS * 16384) {
    int r = gid >> 14;
    int off = gid & 16383;
    int j = off & 7, n = (off >> 3) & 127, kp = off >> 10;
    int k = kp * 8 + j;
    const float* wc = w_comp + r * NUM_BASES;
    float acc = 0.f;
#pragma unroll
    for (int b = 0; b < NUM_BASES; ++b)
      acc += wc[b] * weight[b * 16384 + k * 128 + n];
    Wp[gid] = (__bf16)acc;
  } else {
    int idx = gid - NUM_RELS * 16384;          // 16384 loop-weight elems
    int j = idx & 7, n = (idx >> 3) & 127, kp = idx >> 10;
    Lp[idx] = (__bf16)loop_w[(kp * 8 + j) * 128 + n];
  }
}

__global__ __launch_bounds__(256) void compose_w_f32_kernel(
    const float* __restrict__ weight, const float* __restrict__ w_comp,
    float* __restrict__ W) {
  int idx = blockIdx.x * 256 + threadIdx.x;
  int r = idx >> 14;
  int io = idx & 16383;
  const float* wc = w_comp + r * NUM_BASES;
  float acc = 0.f;
#pragma unroll
  for (int b = 0; b < NUM_BASES; ++b)
    acc += wc[b] * weight[b * 16384 + io];
  W[idx] = acc;
}

// ---------------------------------------------------------------------------
// out[n] = h_bias + feat[n] @ loop_weight   (MFMA bf16, 64 nodes / block)
// Also PRODUCES featb (bf16 feat copy) as a side output when non-null.
// ---------------------------------------------------------------------------
__global__ __launch_bounds__(256) void init_out_mfma(
    const float* __restrict__ feat, __bf16* __restrict__ featb,
    const __bf16* __restrict__ Lp, const float* __restrict__ bias,
    float* __restrict__ out) {
  __shared__ __bf16 A_lds[64 * 136];
  int t = threadIdx.x;
  long base = (long)blockIdx.x * 64;
#pragma unroll
  for (int j = 0; j < 8; ++j) {
    int idx = t + j * 256;
    int e = idx >> 5, k4 = idx & 31;
    long n = base + e;
    float4 v = make_float4(0.f, 0.f, 0.f, 0.f);
    bool ok = (n < N_NODES);
    if (ok) v = ((const float4*)feat)[n * 32 + k4];
    __bf16 tb[4] = {(__bf16)v.x, (__bf16)v.y, (__bf16)v.z, (__bf16)v.w};
    *(ushort4*)&A_lds[e * 136 + k4 * 4] = *(ushort4*)tb;
    if (featb && ok)
      *(ushort4*)(featb + n * 128 + k4 * 4) = *(ushort4*)tb;
  }
  __syncthreads();

  int wave = t >> 6, lane = t & 63;
  int m16 = lane & 15, quad = lane >> 4;
  floatx4 acc[8];
#pragma unroll
  for (int nt = 0; nt < 8; ++nt) acc[nt] = (floatx4){0.f, 0.f, 0.f, 0.f};

  const __bf16* a_base = &A_lds[(wave * 16 + m16) * 136 + quad * 8];
#pragma unroll
  for (int ks = 0; ks < 4; ++ks) {
    bf16x8 a = *(const bf16x8*)(a_base + ks * 32);
    int kp = ks * 4 + quad;
#pragma unroll
    for (int nt = 0; nt < 8; ++nt) {
      bf16x8 b = *(const bf16x8*)(Lp + (kp * 128 + nt * 16 + m16) * 8);
      acc[nt] = __builtin_amdgcn_mfma_f32_16x16x32_bf16(a, b, acc[nt], 0, 0, 0);
    }
  }

  float bv[8];
#pragma unroll
  for (int nt = 0; nt < 8; ++nt) bv[nt] = bias[nt * 16 + m16];
#pragma unroll
  for (int r = 0; r < 4; ++r) {
    long n = base + wave * 16 + quad * 4 + r;
    if (n < N_NODES) {
#pragma unroll
      for (int nt = 0; nt < 8; ++nt)
        out[n * 128 + nt * 16 + m16] = acc[nt][r] + bv[nt];
    }
  }
}

// ---------------------------------------------------------------------------
// Per-chunk CSR build. v7: hist also RECORDS each edge's arrival rank
// (the atomicAdd return) -> CSR slot = row[dst] + rank, so neither a
// scatter_pos pass nor in-GEMM atomics are needed (round-6 regression:
// atomics in edge_gemm cost +12us/dispatch and +16MB writes).
// ---------------------------------------------------------------------------
__global__ __launch_bounds__(256) void zero_kernel(int* __restrict__ p) {
  p[blockIdx.x * 256 + threadIdx.x] = 0;
}

__global__ __launch_bounds__(256) void hist_rank_kernel(
    const int* __restrict__ dst, int* __restrict__ cnt8,
    int* __restrict__ rank, int cshift) {
  int e = blockIdx.x * 256 + threadIdx.x;
  int c = e >> cshift;
  rank[e] = atomicAdd(&cnt8[c * N_PAD + dst[e]], 1);
}

__global__ __launch_bounds__(256) void scan1_kernel(
    const int* __restrict__ cnt, int* __restrict__ row,
    int* __restrict__ bsum) {
  __shared__ int s[256];
  int t = threadIdx.x;
  int idx = blockIdx.x * 256 + t;
  int v = cnt[idx];
  s[t] = v;
  __syncthreads();
  for (int o = 1; o < 256; o <<= 1) {
    int x = (t >= o) ? s[t - o] : 0;
    __syncthreads();
    s[t] += x;
    __syncthreads();
  }
  row[idx] = s[t] - v;
  if (t == 255) bsum[blockIdx.x] = s[t];
}

__global__ __launch_bounds__(512) void scan2_kernel(
    const int* __restrict__ bsum, int* __restrict__ boff) {
  __shared__ int s[512];
  int t = threadIdx.x;
  int v = (t < NBLK) ? bsum[blockIdx.x * NBLK + t] : 0;
  s[t] = v;
  __syncthreads();
  for (int o = 1; o < 512; o <<= 1) {
    int x = (t >= o) ? s[t - o] : 0;
    __syncthreads();
    s[t] += x;
    __syncthreads();
  }
  if (t < NBLK) boff[blockIdx.x * NBLK + t] = s[t] - v;
}

__global__ __launch_bounds__(256) void scan3_kernel(
    int* __restrict__ row, const int* __restrict__ boff) {
  int idx = blockIdx.x * 256 + threadIdx.x;
  row[idx] += boff[blockIdx.x];
}

// ---------------------------------------------------------------------------
// Phase A (MFMA): msg[row[dst[e]]+rank[e]] = bf16((feat[src[e]]@W[rel])*norm)
// Block = TPB(4) consecutive 64-edge tiles of ONE relation; B staged once;
// 2-deep pipeline, no in-loop barriers. Slot math is atomic-free: dst/rank
// sequential reads, rowc's 400KB chunk slice is L2-resident.
// ---------------------------------------------------------------------------
__global__ __launch_bounds__(256) void edge_gemm_mfma(
    const float* __restrict__ feat, const __bf16* __restrict__ featb,
    const __bf16* __restrict__ Wp, const float* __restrict__ norm,
    const int* __restrict__ src, const int* __restrict__ dst,
    const int* __restrict__ rank, const int* __restrict__ rowc,
    unsigned short* __restrict__ msg, int e_lo) {
  __shared__ __bf16 B_lds[IN_FEAT * OUT_FEAT];   // 32 KB, k-packed
  __shared__ __bf16 D_lds[64 * 136];             // 17.4 KB D-bounce
  int t = threadIdx.x;
  long base = (long)e_lo + (long)blockIdx.x * (64 * TPB);
  int rel = (int)(base >> 14);                   // 64*TPB divides 16384
  const __bf16* Wr = Wp + (long)rel * (IN_FEAT * OUT_FEAT);

  // stage B once per block (sequential, L2-hot across 64 blocks/rel)
  {
    const uint4* Wr4 = (const uint4*)Wr;
    uint4* B4 = (uint4*)B_lds;
#pragma unroll
    for (int j = 0; j < 8; ++j) B4[t + j * 256] = Wr4[t + j * 256];
  }

  int wave = t >> 6, lane = t & 63;
  int m16 = lane & 15, quad = lane >> 4;

  bf16x8 aA[4], aB[4];
  float nmA[4], nmB[4];
  int poA[4], poB[4];
  int srow0, srow1;

#define LOAD_SROW(dstv, it) (dstv) = src[base + (it) * 64 + wave * 16 + m16]

#define LOAD_TILE(aX, nmX, poX, it, srowX)                                   \
  do {                                                                       \
    if (featb) {                                                             \
      const __bf16* ap = featb + (long)(srowX)*128 + quad * 8;               \
      _Pragma("unroll") for (int ks = 0; ks < 4; ++ks)                       \
          aX[ks] = *(const bf16x8*)(ap + ks * 32);                           \
    } else {                                                                 \
      const float* fp = feat + (long)(srowX)*128 + quad * 8;                 \
      _Pragma("unroll") for (int ks = 0; ks < 4; ++ks) {                     \
        float4 lo = *(const float4*)(fp + ks * 32);                          \
        float4 hi = *(const float4*)(fp + ks * 32 + 4);                      \
        __bf16 tb[8] = {(__bf16)lo.x, (__bf16)lo.y, (__bf16)lo.z,            \
                        (__bf16)lo.w, (__bf16)hi.x, (__bf16)hi.y,            \
                        (__bf16)hi.z, (__bf16)hi.w};                         \
        aX[ks] = *(bf16x8*)tb;                                               \
      }                                                                      \
    }                                                                        \
    _Pragma("unroll") for (int r = 0; r < 4; ++r)                            \
        nmX[r] = norm[base + (it) * 64 + wave * 16 + quad * 4 + r];          \
    {                                                                        \
      int poMine = 0;                                                        \
      if (lane < 16) {                                                       \
        long ei = base + (it) * 64 + wave * 16 + lane;                       \
        poMine = rowc[dst[ei]] + rank[ei];                                   \
      }                                                                      \
      _Pragma("unroll") for (int i = 0; i < 4; ++i)                          \
          poX[i] = __shfl(poMine, i * 4 + quad);                             \
    }                                                                        \
  } while (0)

#define COMPUTE_TILE(aX, nmX, poX)                                           \
  do {                                                                       \
    floatx4 acc[8];                                                          \
    _Pragma("unroll") for (int nt = 0; nt < 8; ++nt)                         \
        acc[nt] = (floatx4){0.f, 0.f, 0.f, 0.f};                             \
    _Pragma("unroll") for (int ks = 0; ks < 4; ++ks) {                       \
      int kp = ks * 4 + quad;                                                \
      _Pragma("unroll") for (int nt = 0; nt < 8; ++nt) {                     \
        bf16x8 b = *(const bf16x8*)(B_lds + (kp * 128 + nt * 16 + m16) * 8); \
        acc[nt] =                                                            \
            __builtin_amdgcn_mfma_f32_16x16x32_bf16(aX[ks], b, acc[nt],      \
                                                    0, 0, 0);                \
      }                                                                      \
    }                                                                        \
    _Pragma("unroll") for (int r = 0; r < 4; ++r) {                          \
      int erow = wave * 16 + quad * 4 + r;                                   \
      _Pragma("unroll") for (int nt = 0; nt < 8; ++nt)                       \
          D_lds[erow * 136 + nt * 16 + m16] = (__bf16)(acc[nt][r] * nmX[r]); \
    }                                                                        \
    __builtin_amdgcn_wave_barrier();                                         \
    _Pragma("unroll") for (int i = 0; i < 4; ++i) {                          \
      int row = wave * 16 + i * 4 + quad;                                    \
      uint4 v = *(const uint4*)&D_lds[row * 136 + m16 * 8];                  \
      *(uint4*)(msg + (long)poX[i] * 128 + m16 * 8) = v;                     \
    }                                                                        \
    __builtin_amdgcn_wave_barrier();                                         \
  } while (0)

  // -------- software pipeline: src 2 ahead, tile-data 1 ahead --------
  LOAD_SROW(srow0, 0);
  LOAD_SROW(srow1, 1);
  LOAD_TILE(aA, nmA, poA, 0, srow0);
  __syncthreads();  // B_lds ready

  LOAD_TILE(aB, nmB, poB, 1, srow1);
  LOAD_SROW(srow0, 2);
  COMPUTE_TILE(aA, nmA, poA);       // tile 0

  LOAD_TILE(aA, nmA, poA, 2, srow0);
  LOAD_SROW(srow1, 3);
  COMPUTE_TILE(aB, nmB, poB);       // tile 1

  LOAD_TILE(aB, nmB, poB, 3, srow1);
  COMPUTE_TILE(aA, nmA, poA);       // tile 2

  COMPUTE_TILE(aB, nmB, poB);       // tile 3

#undef LOAD_SROW
#undef LOAD_TILE
#undef COMPUTE_TILE
}

// ---------------------------------------------------------------------------
// Phase B: CSR gather, 4 msg rows / iter (uint4/lane = 1KB per wave-iter).
// ---------------------------------------------------------------------------
__global__ __launch_bounds__(256) void gather_csr_kernel(
    const unsigned short* __restrict__ msg, const int* __restrict__ rowc,
    float* __restrict__ out, int do_relu) {
  int wave = threadIdx.x >> 6, lane = threadIdx.x & 63;
  int n = blockIdx.x * 4 + wave;
  if (n >= N_NODES) return;
  int beg = rowc[n], end = rowc[n + 1];
  if (!do_relu && beg == end) return;
  int q = lane >> 4;
  int c8 = lane & 15;
  float s[8] = {0.f, 0.f, 0.f, 0.f, 0.f, 0.f, 0.f, 0.f};
  for (int j = beg; j < end; j += 4) {
    int jr = j + q;
    if (jr < end) {
      uint4 m = *(const uint4*)(msg + (long)jr * 128 + c8 * 8);
      s[0] += __uint_as_float(m.x << 16);
      s[1] += __uint_as_float(m.x & 0xFFFF0000u);
      s[2] += __uint_as_float(m.y << 16);
      s[3] += __uint_as_float(m.y & 0xFFFF0000u);
      s[4] += __uint_as_float(m.z << 16);
      s[5] += __uint_as_float(m.z & 0xFFFF0000u);
      s[6] += __uint_as_float(m.w << 16);
      s[7] += __uint_as_float(m.w & 0xFFFF0000u);
    }
  }
#pragma unroll
  for (int k = 0; k < 8; ++k) {
    s[k] += __shfl_xor(s[k], 16);
    s[k] += __shfl_xor(s[k], 32);
  }
  if (q == 0) {
    float4 o0 = ((float4*)out)[(long)n * 32 + c8 * 2];
    float4 o1 = ((float4*)out)[(long)n * 32 + c8 * 2 + 1];
    o0.x += s[0]; o0.y += s[1]; o0.z += s[2]; o0.w += s[3];
    o1.x += s[4]; o1.y += s[5]; o1.z += s[6]; o1.w += s[7];
    if (do_relu) {
      o0.x = fmaxf(o0.x, 0.f); o0.y = fmaxf(o0.y, 0.f);
      o0.z = fmaxf(o0.z, 0.f); o0.w = fmaxf(o0.w, 0.f);
      o1.x = fmaxf(o1.x, 0.f); o1.y = fmaxf(o1.y, 0.f);
      o1.z = fmaxf(o1.z, 0.f); o1.w = fmaxf(o1.w, 0.f);
    }
    ((float4*)out)[(long)n * 32 + c8 * 2] = o0;
    ((float4*)out)[(long)n * 32 + c8 * 2 + 1] = o1;
  }
}

// ---------------------------------------------------------------------------
// Fallback (tiny ws): fp32 init + GEMM + atomic scatter + relu
// ---------------------------------------------------------------------------
__global__ __launch_bounds__(256) void init_out_f32_kernel(
    const float* __restrict__ feat, const float* __restrict__ loop_w,
    const float* __restrict__ bias, float* __restrict__ out) {
  __shared__ float4 A4[64][32];
  int t = threadIdx.x;
  long base = (long)blockIdx.x * 64;
#pragma unroll
  for (int j = 0; j < 8; ++j) {
    int idx = t + j * 256;
    int e = idx >> 5, k4 = idx & 31;
    long n = base + e;
    float4 v = make_float4(0.f, 0.f, 0.f, 0.f);
    if (n < N_NODES) v = ((const float4*)feat)[n * 32 + k4];
    A4[e][k4] = v;
  }
  __syncthreads();
  int og = t & 31, eg = t >> 5;
  float acc[8][4];
#pragma unroll
  for (int j = 0; j < 8; ++j)
#pragma unroll
    for (int d = 0; d < 4; ++d) acc[j][d] = 0.f;
  const float4* W4 = (const float4*)loop_w;
  for (int k4 = 0; k4 < 32; ++k4) {
    float4 a[8];
#pragma unroll
    for (int j = 0; j < 8; ++j) a[j] = A4[eg * 8 + j][k4];
#pragma unroll
    for (int d = 0; d < 4; ++d) {
      float4 w = W4[(k4 * 4 + d) * 32 + og];
#pragma unroll
      for (int j = 0; j < 8; ++j) {
        float av = ((const float*)&a[j])[d];
        acc[j][0] += av * w.x;
        acc[j][1] += av * w.y;
        acc[j][2] += av * w.z;
        acc[j][3] += av * w.w;
      }
    }
  }
  float4 b = ((const float4*)bias)[og];
#pragma unroll
  for (int j = 0; j < 8; ++j) {
    long n = base + eg * 8 + j;
    if (n < N_NODES) {
      float4 v = make_float4(acc[j][0] + b.x, acc[j][1] + b.y,
                             acc[j][2] + b.z, acc[j][3] + b.w);
      ((float4*)out)[n * 32 + og] = v;
    }
  }
}

__global__ __launch_bounds__(256) void edge_msg_atomic_kernel(
    const float* __restrict__ feat, const float* __restrict__ W,
    const float* __restrict__ norm, const int* __restrict__ src,
    const int* __restrict__ dst, float* __restrict__ out) {
  __shared__ float4 A4[64][32];
  __shared__ int s_src[64];
  __shared__ int s_dst[64];
  __shared__ float s_norm[64];
  int t = threadIdx.x;
  long base = (long)blockIdx.x * 64;
  int rel = blockIdx.x >> 8;
  const float4* Wr4 = (const float4*)(W + (long)rel * IN_FEAT * OUT_FEAT);
  if (t < 64) {
    s_src[t] = src[base + t];
    s_dst[t] = dst[base + t];
    s_norm[t] = norm[base + t];
  }
  __syncthreads();
#pragma unroll
  for (int j = 0; j < 8; ++j) {
    int idx = t + j * 256;
    int e = idx >> 5, k4 = idx & 31;
    A4[e][k4] = ((const float4*)feat)[(long)s_src[e] * 32 + k4];
  }
  __syncthreads();
  int og = t & 31, eg = t >> 5;
  float acc[8][4];
#pragma unroll
  for (int j = 0; j < 8; ++j)
#pragma unroll
    for (int d = 0; d < 4; ++d) acc[j][d] = 0.f;
  for (int k4 = 0; k4 < 32; ++k4) {
    float4 a[8];
#pragma unroll
    for (int j = 0; j < 8; ++j) a[j] = A4[eg * 8 + j][k4];
#pragma unroll
    for (int d = 0; d < 4; ++d) {
      float4 w = Wr4[(k4 * 4 + d) * 32 + og];
#pragma unroll
      for (int j = 0; j < 8; ++j) {
        float av = ((const float*)&a[j])[d];
        acc[j][0] += av * w.x;
        acc[j][1] += av * w.y;
        acc[j][2] += av * w.z;
        acc[j][3] += av * w.w;
      }
    }
  }
#pragma unroll
  for (int j = 0; j < 8; ++j) {
    int e = eg * 8 + j;
    float nm = s_norm[e];
    float* orow = out + (long)s_dst[e] * OUT_FEAT + og * 4;
#pragma unroll
    for (int d = 0; d < 4; ++d) atomicAdd(orow + d, acc[j][d] * nm);
  }
}

__global__ __launch_bounds__(256) void relu_kernel(float* __restrict__ out) {
  int idx = blockIdx.x * 256 + threadIdx.x;
  float4 v = ((const float4*)out)[idx];
  v.x = fmaxf(v.x, 0.f);
  v.y = fmaxf(v.y, 0.f);
  v.z = fmaxf(v.z, 0.f);
  v.w = fmaxf(v.w, 0.f);
  ((float4*)out)[idx] = v;
}

extern "C" void kernel_launch(void* const* d_in, const int* in_sizes, int n_in,
                              void* d_out, int out_size, void* d_ws, size_t ws_size,
                              hipStream_t stream) {
  const float* feat   = (const float*)d_in[0];
  const float* weight = (const float*)d_in[1];
  const float* w_comp = (const float*)d_in[2];
  const float* h_bias = (const float*)d_in[3];
  const float* loop_w = (const float*)d_in[4];
  const float* norm   = (const float*)d_in[5];
  const int*   src    = (const int*)d_in[6];
  const int*   dst    = (const int*)d_in[7];
  float* out = (float*)d_out;

  const size_t SZ_WP   = (size_t)NUM_RELS * IN_FEAT * OUT_FEAT * 2;  // 2 MB
  const size_t SZ_LP   = (size_t)IN_FEAT * OUT_FEAT * 2;             // 32 KB
  const size_t SZ_FB   = (size_t)N_NODES * IN_FEAT * 2;              // 25.6 MB
  const size_t SZ_RANK = (size_t)E_TOTAL * 4;                        // 4 MB

  // Config ladder: fewest out-RMW passes first, then the bf16-feat copy.
  int CH = 0, FB = 0;
  {
    const int chs[11] = {64, 64, 32, 32, 16, 16, 8, 8, 4, 4, 0};
    const int fbs[11] = { 1,  0,  1,  0,  1,  0, 1, 0, 1, 0, 0};
    for (int i = 0; i < 10 && CH == 0; ++i) {
      int ch = chs[i], fb = fbs[i], nc = NUM_RELS / ch;
      size_t need = SZ_WP + SZ_LP + (fb ? SZ_FB : 0) + SZ_RANK +
                    2 * (size_t)nc * N_PAD * 4 + 2 * (size_t)nc * NBLK * 4 +
                    (size_t)ch * EDGES_PER_REL * OUT_FEAT * 2;
      if (ws_size >= need) { CH = ch; FB = fb; }
    }
  }

  if (CH > 0) {
    const int NC = NUM_RELS / CH;
    const int chunk_edges = CH * EDGES_PER_REL;
    int cshift = 14;
    for (int x = CH; x > 1; x >>= 1) ++cshift;

    char* p = (char*)d_ws;
    __bf16* Wp = (__bf16*)p;                  p += SZ_WP;
    __bf16* Lp = (__bf16*)p;                  p += SZ_LP;
    __bf16* featb = nullptr;
    if (FB) { featb = (__bf16*)p;             p += SZ_FB; }
    int* rank = (int*)p;                      p += SZ_RANK;
    int* cnt8 = (int*)p;                      p += (size_t)NC * N_PAD * 4;
    int* row8 = (int*)p;                      p += (size_t)NC * N_PAD * 4;
    int* bsum = (int*)p;                      p += (size_t)NC * NBLK * 4;
    int* boff = (int*)p;                      p += (size_t)NC * NBLK * 4;
    unsigned short* msg = (unsigned short*)p;

    hipLaunchKernelGGL(compose_all_bf16_kernel,
                       dim3((NUM_RELS * 16384 + 16384) / 256), dim3(256), 0,
                       stream, weight, w_comp, loop_w, Wp, Lp);
    hipLaunchKernelGGL(init_out_mfma, dim3((N_NODES + 63) / 64), dim3(256), 0,
                       stream, feat, featb, Lp, h_bias, out);
    hipLaunchKernelGGL(zero_kernel, dim3(NC * NBLK), dim3(256), 0, stream, cnt8);
    hipLaunchKernelGGL(hist_rank_kernel, dim3(E_TOTAL / 256), dim3(256), 0,
                       stream, dst, cnt8, rank, cshift);
    hipLaunchKernelGGL(scan1_kernel, dim3(NC * NBLK), dim3(256), 0, stream,
                       cnt8, row8, bsum);
    hipLaunchKernelGGL(scan2_kernel, dim3(NC), dim3(512), 0, stream, bsum, boff);
    hipLaunchKernelGGL(scan3_kernel, dim3(NC * NBLK), dim3(256), 0, stream,
                       row8, boff);

    for (int c = 0; c < NC; ++c) {
      hipLaunchKernelGGL(edge_gemm_mfma, dim3(chunk_edges / (64 * TPB)),
                         dim3(256), 0, stream, feat, featb, Wp, norm, src, dst,
                         rank, row8 + (size_t)c * N_PAD, msg, c * chunk_edges);
      hipLaunchKernelGGL(gather_csr_kernel, dim3((N_NODES + 3) / 4), dim3(256),
                         0, stream, msg, row8 + (size_t)c * N_PAD, out,
                         (c == NC - 1) ? 1 : 0);
    }
  } else {
    float* W = (float*)d_ws;
    hipLaunchKernelGGL(init_out_f32_kernel, dim3((N_NODES + 63) / 64),
                       dim3(256), 0, stream, feat, loop_w, h_bias, out);
    hipLaunchKernelGGL(compose_w_f32_kernel, dim3(NUM_RELS * 16384 / 256),
                       dim3(256), 0, stream, weight, w_comp, W);
    hipLaunchKernelGGL(edge_msg_atomic_kernel, dim3(E_TOTAL / 64), dim3(256), 0,
                       stream, feat, W, norm, src, dst, out);
    hipLaunchKernelGGL(relu_kernel, dim3((N_NODES * OUT_FEAT / 4) / 256),
                       dim3(256), 0, stream, out);
  }
}

// Round 8
// 384.113 us; speedup vs baseline: 1.2019x; 1.0207x over previous
//
#include <hip/hip_runtime.h>

#define N_NODES 100000
#define N_PAD 100352          // 392 * 256
#define NBLK 392
#define IN_FEAT 128
#define OUT_FEAT 128
#define NUM_RELS 64
#define EDGES_PER_REL 16384
#define NUM_BASES 16
#define E_TOTAL (NUM_RELS * EDGES_PER_REL)
#define TPB 4                 // 64-edge tiles per block in edge_gemm (256 edges)

typedef __bf16 bf16x8 __attribute__((ext_vector_type(8)));
typedef float floatx4 __attribute__((ext_vector_type(4)));

// ---------------------------------------------------------------------------
// Fused W composition (bf16 k-packed Wp[r][kp][n][j]) + loop_weight pack.
// ---------------------------------------------------------------------------
__global__ __launch_bounds__(256) void compose_all_bf16_kernel(
    const float* __restrict__ weight, const float* __restrict__ w_comp,
    const float* __restrict__ loop_w, __bf16* __restrict__ Wp,
    __bf16* __restrict__ Lp) {
  int gid = blockIdx.x * 256 + threadIdx.x;
  if (gid < NUM_RELS * 16384) {
    int r = gid >> 14;
    int off = gid & 16383;
    int j = off & 7, n = (off >> 3) & 127, kp = off >> 10;
    int k = kp * 8 + j;
    const float* wc = w_comp + r * NUM_BASES;
    float acc = 0.f;
#pragma unroll
    for (int b = 0; b < NUM_BASES; ++b)
      acc += wc[b] * weight[b * 16384 + k * 128 + n];
    Wp[gid] = (__bf16)acc;
  } else {
    int idx = gid - NUM_RELS * 16384;          // 16384 loop-weight elems
    int j = idx & 7, n = (idx >> 3) & 127, kp = idx >> 10;
    Lp[idx] = (__bf16)loop_w[(kp * 8 + j) * 128 + n];
  }
}

__global__ __launch_bounds__(256) void compose_w_f32_kernel(
    const float* __restrict__ weight, const float* __restrict__ w_comp,
    float* __restrict__ W) {
  int idx = blockIdx.x * 256 + threadIdx.x;
  int r = idx >> 14;
  int io = idx & 16383;
  const float* wc = w_comp + r * NUM_BASES;
  float acc = 0.f;
#pragma unroll
  for (int b = 0; b < NUM_BASES; ++b)
    acc += wc[b] * weight[b * 16384 + io];
  W[idx] = acc;
}

// ---------------------------------------------------------------------------
// out[n] = h_bias + feat[n] @ loop_weight   (MFMA bf16, 64 nodes / block)
// Also PRODUCES featb (bf16 feat copy) as a side output when non-null.
// ---------------------------------------------------------------------------
__global__ __launch_bounds__(256) void init_out_mfma(
    const float* __restrict__ feat, __bf16* __restrict__ featb,
    const __bf16* __restrict__ Lp, const float* __restrict__ bias,
    float* __restrict__ out) {
  __shared__ __bf16 A_lds[64 * 136];
  int t = threadIdx.x;
  long base = (long)blockIdx.x * 64;
#pragma unroll
  for (int j = 0; j < 8; ++j) {
    int idx = t + j * 256;
    int e = idx >> 5, k4 = idx & 31;
    long n = base + e;
    float4 v = make_float4(0.f, 0.f, 0.f, 0.f);
    bool ok = (n < N_NODES);
    if (ok) v = ((const float4*)feat)[n * 32 + k4];
    __bf16 tb[4] = {(__bf16)v.x, (__bf16)v.y, (__bf16)v.z, (__bf16)v.w};
    *(ushort4*)&A_lds[e * 136 + k4 * 4] = *(ushort4*)tb;
    if (featb && ok)
      *(ushort4*)(featb + n * 128 + k4 * 4) = *(ushort4*)tb;
  }
  __syncthreads();

  int wave = t >> 6, lane = t & 63;
  int m16 = lane & 15, quad = lane >> 4;
  floatx4 acc[8];
#pragma unroll
  for (int nt = 0; nt < 8; ++nt) acc[nt] = (floatx4){0.f, 0.f, 0.f, 0.f};

  const __bf16* a_base = &A_lds[(wave * 16 + m16) * 136 + quad * 8];
#pragma unroll
  for (int ks = 0; ks < 4; ++ks) {
    bf16x8 a = *(const bf16x8*)(a_base + ks * 32);
    int kp = ks * 4 + quad;
#pragma unroll
    for (int nt = 0; nt < 8; ++nt) {
      bf16x8 b = *(const bf16x8*)(Lp + (kp * 128 + nt * 16 + m16) * 8);
      acc[nt] = __builtin_amdgcn_mfma_f32_16x16x32_bf16(a, b, acc[nt], 0, 0, 0);
    }
  }

  float bv[8];
#pragma unroll
  for (int nt = 0; nt < 8; ++nt) bv[nt] = bias[nt * 16 + m16];
#pragma unroll
  for (int r = 0; r < 4; ++r) {
    long n = base + wave * 16 + quad * 4 + r;
    if (n < N_NODES) {
#pragma unroll
      for (int nt = 0; nt < 8; ++nt)
        out[n * 128 + nt * 16 + m16] = acc[nt][r] + bv[nt];
    }
  }
}

// ---------------------------------------------------------------------------
// Per-chunk CSR build. v8: hist records each edge's arrival rank (atomicAdd
// return); after the scan, pos_fix finalizes IN-PLACE: rank[e] += row[dst[e]]
// -> rank becomes the absolute CSR slot. No scatter_pos atomics pass, no
// extra pos array, and edge_gemm gets a clean sequential slot read (round-7
// regression: inline rowc[dst[e]] gather on the store-address critical path
// cost +8.5us/dispatch).
// ---------------------------------------------------------------------------
__global__ __launch_bounds__(256) void zero_kernel(int* __restrict__ p) {
  p[blockIdx.x * 256 + threadIdx.x] = 0;
}

__global__ __launch_bounds__(256) void hist_rank_kernel(
    const int* __restrict__ dst, int* __restrict__ cnt8,
    int* __restrict__ rank, int cshift) {
  int e = blockIdx.x * 256 + threadIdx.x;
  int c = e >> cshift;
  rank[e] = atomicAdd(&cnt8[c * N_PAD + dst[e]], 1);
}

__global__ __launch_bounds__(256) void scan1_kernel(
    const int* __restrict__ cnt, int* __restrict__ row,
    int* __restrict__ bsum) {
  __shared__ int s[256];
  int t = threadIdx.x;
  int idx = blockIdx.x * 256 + t;
  int v = cnt[idx];
  s[t] = v;
  __syncthreads();
  for (int o = 1; o < 256; o <<= 1) {
    int x = (t >= o) ? s[t - o] : 0;
    __syncthreads();
    s[t] += x;
    __syncthreads();
  }
  row[idx] = s[t] - v;
  if (t == 255) bsum[blockIdx.x] = s[t];
}

__global__ __launch_bounds__(512) void scan2_kernel(
    const int* __restrict__ bsum, int* __restrict__ boff) {
  __shared__ int s[512];
  int t = threadIdx.x;
  int v = (t < NBLK) ? bsum[blockIdx.x * NBLK + t] : 0;
  s[t] = v;
  __syncthreads();
  for (int o = 1; o < 512; o <<= 1) {
    int x = (t >= o) ? s[t - o] : 0;
    __syncthreads();
    s[t] += x;
    __syncthreads();
  }
  if (t < NBLK) boff[blockIdx.x * NBLK + t] = s[t] - v;
}

__global__ __launch_bounds__(256) void scan3_kernel(
    int* __restrict__ row, const int* __restrict__ boff) {
  int idx = blockIdx.x * 256 + threadIdx.x;
  row[idx] += boff[blockIdx.x];
}

// rank[e] += row[chunk(e)*N_PAD + dst[e]]  -> absolute CSR slot (in-place)
__global__ __launch_bounds__(256) void pos_fix_kernel(
    const int* __restrict__ dst, const int* __restrict__ row8,
    int* __restrict__ rank, int cshift) {
  int e = blockIdx.x * 256 + threadIdx.x;
  int c = e >> cshift;
  rank[e] += row8[(size_t)c * N_PAD + dst[e]];
}

// ---------------------------------------------------------------------------
// Phase A (MFMA): msg[pos[e]] = bf16((feat[src[e]] @ W[rel]) * norm[e])
// Round-5 structure (fastest measured: 54.1us): block = TPB(4) consecutive
// 64-edge tiles of ONE relation; B staged once; 2-deep pipeline, no in-loop
// barriers; sequential pos read (rank[] after pos_fix).
// ---------------------------------------------------------------------------
__global__ __launch_bounds__(256) void edge_gemm_mfma(
    const float* __restrict__ feat, const __bf16* __restrict__ featb,
    const __bf16* __restrict__ Wp, const float* __restrict__ norm,
    const int* __restrict__ src, const int* __restrict__ pos,
    unsigned short* __restrict__ msg, int e_lo) {
  __shared__ __bf16 B_lds[IN_FEAT * OUT_FEAT];   // 32 KB, k-packed
  __shared__ __bf16 D_lds[64 * 136];             // 17.4 KB D-bounce
  int t = threadIdx.x;
  long base = (long)e_lo + (long)blockIdx.x * (64 * TPB);
  int rel = (int)(base >> 14);                   // 64*TPB divides 16384
  const __bf16* Wr = Wp + (long)rel * (IN_FEAT * OUT_FEAT);

  // stage B once per block (sequential, L2-hot across 64 blocks/rel)
  {
    const uint4* Wr4 = (const uint4*)Wr;
    uint4* B4 = (uint4*)B_lds;
#pragma unroll
    for (int j = 0; j < 8; ++j) B4[t + j * 256] = Wr4[t + j * 256];
  }

  int wave = t >> 6, lane = t & 63;
  int m16 = lane & 15, quad = lane >> 4;

  bf16x8 aA[4], aB[4];
  float nmA[4], nmB[4];
  int poA[4], poB[4];
  int srow0, srow1;

#define LOAD_SROW(dstv, it) (dstv) = src[base + (it) * 64 + wave * 16 + m16]

#define LOAD_TILE(aX, nmX, poX, it, srowX)                                   \
  do {                                                                       \
    if (featb) {                                                             \
      const __bf16* ap = featb + (long)(srowX)*128 + quad * 8;               \
      _Pragma("unroll") for (int ks = 0; ks < 4; ++ks)                       \
          aX[ks] = *(const bf16x8*)(ap + ks * 32);                           \
    } else {                                                                 \
      const float* fp = feat + (long)(srowX)*128 + quad * 8;                 \
      _Pragma("unroll") for (int ks = 0; ks < 4; ++ks) {                     \
        float4 lo = *(const float4*)(fp + ks * 32);                          \
        float4 hi = *(const float4*)(fp + ks * 32 + 4);                      \
        __bf16 tb[8] = {(__bf16)lo.x, (__bf16)lo.y, (__bf16)lo.z,            \
                        (__bf16)lo.w, (__bf16)hi.x, (__bf16)hi.y,            \
                        (__bf16)hi.z, (__bf16)hi.w};                         \
        aX[ks] = *(bf16x8*)tb;                                               \
      }                                                                      \
    }                                                                        \
    _Pragma("unroll") for (int r = 0; r < 4; ++r)                            \
        nmX[r] = norm[base + (it) * 64 + wave * 16 + quad * 4 + r];          \
    _Pragma("unroll") for (int i = 0; i < 4; ++i)                            \
        poX[i] = pos[base + (it) * 64 + wave * 16 + i * 4 + quad];           \
  } while (0)

#define COMPUTE_TILE(aX, nmX, poX)                                           \
  do {                                                                       \
    floatx4 acc[8];                                                          \
    _Pragma("unroll") for (int nt = 0; nt < 8; ++nt)                         \
        acc[nt] = (floatx4){0.f, 0.f, 0.f, 0.f};                             \
    _Pragma("unroll") for (int ks = 0; ks < 4; ++ks) {                       \
      int kp = ks * 4 + quad;                                                \
      _Pragma("unroll") for (int nt = 0; nt < 8; ++nt) {                     \
        bf16x8 b = *(const bf16x8*)(B_lds + (kp * 128 + nt * 16 + m16) * 8); \
        acc[nt] =                                                            \
            __builtin_amdgcn_mfma_f32_16x16x32_bf16(aX[ks], b, acc[nt],      \
                                                    0, 0, 0);                \
      }                                                                      \
    }                                                                        \
    _Pragma("unroll") for (int r = 0; r < 4; ++r) {                          \
      int erow = wave * 16 + quad * 4 + r;                                   \
      _Pragma("unroll") for (int nt = 0; nt < 8; ++nt)                       \
          D_lds[erow * 136 + nt * 16 + m16] = (__bf16)(acc[nt][r] * nmX[r]); \
    }                                                                        \
    __builtin_amdgcn_wave_barrier();                                         \
    _Pragma("unroll") for (int i = 0; i < 4; ++i) {                          \
      int row = wave * 16 + i * 4 + quad;                                    \
      uint4 v = *(const uint4*)&D_lds[row * 136 + m16 * 8];                  \
      *(uint4*)(msg + (long)poX[i] * 128 + m16 * 8) = v;                     \
    }                                                                        \
    __builtin_amdgcn_wave_barrier();                                         \
  } while (0)

  // -------- software pipeline: src 2 ahead, tile-data 1 ahead --------
  LOAD_SROW(srow0, 0);
  LOAD_SROW(srow1, 1);
  LOAD_TILE(aA, nmA, poA, 0, srow0);
  __syncthreads();  // B_lds ready

  LOAD_TILE(aB, nmB, poB, 1, srow1);
  LOAD_SROW(srow0, 2);
  COMPUTE_TILE(aA, nmA, poA);       // tile 0

  LOAD_TILE(aA, nmA, poA, 2, srow0);
  LOAD_SROW(srow1, 3);
  COMPUTE_TILE(aB, nmB, poB);       // tile 1

  LOAD_TILE(aB, nmB, poB, 3, srow1);
  COMPUTE_TILE(aA, nmA, poA);       // tile 2

  COMPUTE_TILE(aB, nmB, poB);       // tile 3

#undef LOAD_SROW
#undef LOAD_TILE
#undef COMPUTE_TILE
}

// ---------------------------------------------------------------------------
// Phase B: CSR gather, 4 msg rows / iter (uint4/lane = 1KB per wave-iter).
// ---------------------------------------------------------------------------
__global__ __launch_bounds__(256) void gather_csr_kernel(
    const unsigned short* __restrict__ msg, const int* __restrict__ rowc,
    float* __restrict__ out, int do_relu) {
  int wave = threadIdx.x >> 6, lane = threadIdx.x & 63;
  int n = blockIdx.x * 4 + wave;
  if (n >= N_NODES) return;
  int beg = rowc[n], end = rowc[n + 1];
  if (!do_relu && beg == end) return;
  int q = lane >> 4;
  int c8 = lane & 15;
  float s[8] = {0.f, 0.f, 0.f, 0.f, 0.f, 0.f, 0.f, 0.f};
  for (int j = beg; j < end; j += 4) {
    int jr = j + q;
    if (jr < end) {
      uint4 m = *(const uint4*)(msg + (long)jr * 128 + c8 * 8);
      s[0] += __uint_as_float(m.x << 16);
      s[1] += __uint_as_float(m.x & 0xFFFF0000u);
      s[2] += __uint_as_float(m.y << 16);
      s[3] += __uint_as_float(m.y & 0xFFFF0000u);
      s[4] += __uint_as_float(m.z << 16);
      s[5] += __uint_as_float(m.z & 0xFFFF0000u);
      s[6] += __uint_as_float(m.w << 16);
      s[7] += __uint_as_float(m.w & 0xFFFF0000u);
    }
  }
#pragma unroll
  for (int k = 0; k < 8; ++k) {
    s[k] += __shfl_xor(s[k], 16);
    s[k] += __shfl_xor(s[k], 32);
  }
  if (q == 0) {
    float4 o0 = ((float4*)out)[(long)n * 32 + c8 * 2];
    float4 o1 = ((float4*)out)[(long)n * 32 + c8 * 2 + 1];
    o0.x += s[0]; o0.y += s[1]; o0.z += s[2]; o0.w += s[3];
    o1.x += s[4]; o1.y += s[5]; o1.z += s[6]; o1.w += s[7];
    if (do_relu) {
      o0.x = fmaxf(o0.x, 0.f); o0.y = fmaxf(o0.y, 0.f);
      o0.z = fmaxf(o0.z, 0.f); o0.w = fmaxf(o0.w, 0.f);
      o1.x = fmaxf(o1.x, 0.f); o1.y = fmaxf(o1.y, 0.f);
      o1.z = fmaxf(o1.z, 0.f); o1.w = fmaxf(o1.w, 0.f);
    }
    ((float4*)out)[(long)n * 32 + c8 * 2] = o0;
    ((float4*)out)[(long)n * 32 + c8 * 2 + 1] = o1;
  }
}

// ---------------------------------------------------------------------------
// Fallback (tiny ws): fp32 init + GEMM + atomic scatter + relu
// ---------------------------------------------------------------------------
__global__ __launch_bounds__(256) void init_out_f32_kernel(
    const float* __restrict__ feat, const float* __restrict__ loop_w,
    const float* __restrict__ bias, float* __restrict__ out) {
  __shared__ float4 A4[64][32];
  int t = threadIdx.x;
  long base = (long)blockIdx.x * 64;
#pragma unroll
  for (int j = 0; j < 8; ++j) {
    int idx = t + j * 256;
    int e = idx >> 5, k4 = idx & 31;
    long n = base + e;
    float4 v = make_float4(0.f, 0.f, 0.f, 0.f);
    if (n < N_NODES) v = ((const float4*)feat)[n * 32 + k4];
    A4[e][k4] = v;
  }
  __syncthreads();
  int og = t & 31, eg = t >> 5;
  float acc[8][4];
#pragma unroll
  for (int j = 0; j < 8; ++j)
#pragma unroll
    for (int d = 0; d < 4; ++d) acc[j][d] = 0.f;
  const float4* W4 = (const float4*)loop_w;
  for (int k4 = 0; k4 < 32; ++k4) {
    float4 a[8];
#pragma unroll
    for (int j = 0; j < 8; ++j) a[j] = A4[eg * 8 + j][k4];
#pragma unroll
    for (int d = 0; d < 4; ++d) {
      float4 w = W4[(k4 * 4 + d) * 32 + og];
#pragma unroll
      for (int j = 0; j < 8; ++j) {
        float av = ((const float*)&a[j])[d];
        acc[j][0] += av * w.x;
        acc[j][1] += av * w.y;
        acc[j][2] += av * w.z;
        acc[j][3] += av * w.w;
      }
    }
  }
  float4 b = ((const float4*)bias)[og];
#pragma unroll
  for (int j = 0; j < 8; ++j) {
    long n = base + eg * 8 + j;
    if (n < N_NODES) {
      float4 v = make_float4(acc[j][0] + b.x, acc[j][1] + b.y,
                             acc[j][2] + b.z, acc[j][3] + b.w);
      ((float4*)out)[n * 32 + og] = v;
    }
  }
}

__global__ __launch_bounds__(256) void edge_msg_atomic_kernel(
    const float* __restrict__ feat, const float* __restrict__ W,
    const float* __restrict__ norm, const int* __restrict__ src,
    const int* __restrict__ dst, float* __restrict__ out) {
  __shared__ float4 A4[64][32];
  __shared__ int s_src[64];
  __shared__ int s_dst[64];
  __shared__ float s_norm[64];
  int t = threadIdx.x;
  long base = (long)blockIdx.x * 64;
  int rel = blockIdx.x >> 8;
  const float4* Wr4 = (const float4*)(W + (long)rel * IN_FEAT * OUT_FEAT);
  if (t < 64) {
    s_src[t] = src[base + t];
    s_dst[t] = dst[base + t];
    s_norm[t] = norm[base + t];
  }
  __syncthreads();
#pragma unroll
  for (int j = 0; j < 8; ++j) {
    int idx = t + j * 256;
    int e = idx >> 5, k4 = idx & 31;
    A4[e][k4] = ((const float4*)feat)[(long)s_src[e] * 32 + k4];
  }
  __syncthreads();
  int og = t & 31, eg = t >> 5;
  float acc[8][4];
#pragma unroll
  for (int j = 0; j < 8; ++j)
#pragma unroll
    for (int d = 0; d < 4; ++d) acc[j][d] = 0.f;
  for (int k4 = 0; k4 < 32; ++k4) {
    float4 a[8];
#pragma unroll
    for (int j = 0; j < 8; ++j) a[j] = A4[eg * 8 + j][k4];
#pragma unroll
    for (int d = 0; d < 4; ++d) {
      float4 w = Wr4[(k4 * 4 + d) * 32 + og];
#pragma unroll
      for (int j = 0; j < 8; ++j) {
        float av = ((const float*)&a[j])[d];
        acc[j][0] += av * w.x;
        acc[j][1] += av * w.y;
        acc[j][2] += av * w.z;
        acc[j][3] += av * w.w;
      }
    }
  }
#pragma unroll
  for (int j = 0; j < 8; ++j) {
    int e = eg * 8 + j;
    float nm = s_norm[e];
    float* orow = out + (long)s_dst[e] * OUT_FEAT + og * 4;
#pragma unroll
    for (int d = 0; d < 4; ++d) atomicAdd(orow + d, acc[j][d] * nm);
  }
}

__global__ __launch_bounds__(256) void relu_kernel(float* __restrict__ out) {
  int idx = blockIdx.x * 256 + threadIdx.x;
  float4 v = ((const float4*)out)[idx];
  v.x = fmaxf(v.x, 0.f);
  v.y = fmaxf(v.y, 0.f);
  v.z = fmaxf(v.z, 0.f);
  v.w = fmaxf(v.w, 0.f);
  ((float4*)out)[idx] = v;
}

extern "C" void kernel_launch(void* const* d_in, const int* in_sizes, int n_in,
                              void* d_out, int out_size, void* d_ws, size_t ws_size,
                              hipStream_t stream) {
  const float* feat   = (const float*)d_in[0];
  const float* weight = (const float*)d_in[1];
  const float* w_comp = (const float*)d_in[2];
  const float* h_bias = (const float*)d_in[3];
  const float* loop_w = (const float*)d_in[4];
  const float* norm   = (const float*)d_in[5];
  const int*   src    = (const int*)d_in[6];
  const int*   dst    = (const int*)d_in[7];
  float* out = (float*)d_out;

  const size_t SZ_WP   = (size_t)NUM_RELS * IN_FEAT * OUT_FEAT * 2;  // 2 MB
  const size_t SZ_LP   = (size_t)IN_FEAT * OUT_FEAT * 2;             // 32 KB
  const size_t SZ_FB   = (size_t)N_NODES * IN_FEAT * 2;              // 25.6 MB
  const size_t SZ_RANK = (size_t)E_TOTAL * 4;                        // 4 MB

  // Config ladder: fewest out-RMW passes first, then the bf16-feat copy.
  int CH = 0, FB = 0;
  {
    const int chs[11] = {64, 64, 32, 32, 16, 16, 8, 8, 4, 4, 0};
    const int fbs[11] = { 1,  0,  1,  0,  1,  0, 1, 0, 1, 0, 0};
    for (int i = 0; i < 10 && CH == 0; ++i) {
      int ch = chs[i], fb = fbs[i], nc = NUM_RELS / ch;
      size_t need = SZ_WP + SZ_LP + (fb ? SZ_FB : 0) + SZ_RANK +
                    2 * (size_t)nc * N_PAD * 4 + 2 * (size_t)nc * NBLK * 4 +
                    (size_t)ch * EDGES_PER_REL * OUT_FEAT * 2;
      if (ws_size >= need) { CH = ch; FB = fb; }
    }
  }

  if (CH > 0) {
    const int NC = NUM_RELS / CH;
    const int chunk_edges = CH * EDGES_PER_REL;
    int cshift = 14;
    for (int x = CH; x > 1; x >>= 1) ++cshift;

    char* p = (char*)d_ws;
    __bf16* Wp = (__bf16*)p;                  p += SZ_WP;
    __bf16* Lp = (__bf16*)p;                  p += SZ_LP;
    __bf16* featb = nullptr;
    if (FB) { featb = (__bf16*)p;             p += SZ_FB; }
    int* rank = (int*)p;                      p += SZ_RANK;
    int* cnt8 = (int*)p;                      p += (size_t)NC * N_PAD * 4;
    int* row8 = (int*)p;                      p += (size_t)NC * N_PAD * 4;
    int* bsum = (int*)p;                      p += (size_t)NC * NBLK * 4;
    int* boff = (int*)p;                      p += (size_t)NC * NBLK * 4;
    unsigned short* msg = (unsigned short*)p;

    hipLaunchKernelGGL(compose_all_bf16_kernel,
                       dim3((NUM_RELS * 16384 + 16384) / 256), dim3(256), 0,
                       stream, weight, w_comp, loop_w, Wp, Lp);
    hipLaunchKernelGGL(init_out_mfma, dim3((N_NODES + 63) / 64), dim3(256), 0,
                       stream, feat, featb, Lp, h_bias, out);
    hipLaunchKernelGGL(zero_kernel, dim3(NC * NBLK), dim3(256), 0, stream, cnt8);
    hipLaunchKernelGGL(hist_rank_kernel, dim3(E_TOTAL / 256), dim3(256), 0,
                       stream, dst, cnt8, rank, cshift);
    hipLaunchKernelGGL(scan1_kernel, dim3(NC * NBLK), dim3(256), 0, stream,
                       cnt8, row8, bsum);
    hipLaunchKernelGGL(scan2_kernel, dim3(NC), dim3(512), 0, stream, bsum, boff);
    hipLaunchKernelGGL(scan3_kernel, dim3(NC * NBLK), dim3(256), 0, stream,
                       row8, boff);
    hipLaunchKernelGGL(pos_fix_kernel, dim3(E_TOTAL / 256), dim3(256), 0,
                       stream, dst, row8, rank, cshift);

    for (int c = 0; c < NC; ++c) {
      hipLaunchKernelGGL(edge_gemm_mfma, dim3(chunk_edges / (64 * TPB)),
                         dim3(256), 0, stream, feat, featb, Wp, norm, src,
                         rank, msg, c * chunk_edges);
      hipLaunchKernelGGL(gather_csr_kernel, dim3((N_NODES + 3) / 4), dim3(256),
                         0, stream, msg, row8 + (size_t)c * N_PAD, out,
                         (c == NC - 1) ? 1 : 0);
    }
  } else {
    float* W = (float*)d_ws;
    hipLaunchKernelGGL(init_out_f32_kernel, dim3((N_NODES + 63) / 64),
                       dim3(256), 0, stream, feat, loop_w, h_bias, out);
    hipLaunchKernelGGL(compose_w_f32_kernel, dim3(NUM_RELS * 16384 / 256),
                       dim3(256), 0, stream, weight, w_comp, W);
    hipLaunchKernelGGL(edge_msg_atomic_kernel, dim3(E_TOTAL / 64), dim3(256), 0,
                       stream, feat, W, norm, src, dst, out);
    hipLaunchKernelGGL(relu_kernel, dim3((N_NODES * OUT_FEAT / 4) / 256),
                       dim3(256), 0, stream, out);
  }
}